// Round 1
// baseline (1038.113 us; speedup 1.0000x reference)
//
#include <hip/hip_runtime.h>

#define LL 8192

__device__ __forceinline__ float4 ld4(const float* p) {
    return *reinterpret_cast<const float4*>(p);
}

// ---------------------------------------------------------------------------
// Kernel A: per-batch channel attention -> fused matrix M = W2bn * (I + beta*A)
// grid = 256 (one block per batch), block = 256
// ---------------------------------------------------------------------------
__global__ __launch_bounds__(256) void kernA(
    const float* __restrict__ x, const float* __restrict__ wc1,
    const float* __restrict__ g1, const float* __restrict__ bt1,
    const float* __restrict__ m1, const float* __restrict__ v1,
    const float* __restrict__ beta_cam, const float* __restrict__ wc2,
    const float* __restrict__ g2, const float* __restrict__ bt2,
    const float* __restrict__ m2, const float* __restrict__ v2,
    float* __restrict__ Mout)
{
    __shared__ float xs[4][512];
    __shared__ float c0t[512][20];   // pad 20: float4 reads spread across banks
    __shared__ float part[4][4][64];
    __shared__ float gram[16][16];
    __shared__ float attn[16][16];
    __shared__ float wf1[16][4];
    __shared__ float bf1[16];

    const int b = blockIdx.x;
    const int t = threadIdx.x;
    const float* xb = x + (size_t)b * 4 * LL;

    if (t < 16) {
        float inv = g1[t] * rsqrtf(v1[t] + 1e-5f);
        #pragma unroll
        for (int c = 0; c < 4; ++c) wf1[t][c] = wc1[t * 4 + c] * inv;
        bf1[t] = bt1[t] - m1[t] * inv;
    }
    __syncthreads();

    float acc[8][8];
    #pragma unroll
    for (int i = 0; i < 8; ++i)
        #pragma unroll
        for (int j = 0; j < 8; ++j) acc[i][j] = 0.f;

    const int q = t & 3, g = t >> 2;
    const int cg = q >> 1, dg = q & 1;

    for (int tile = 0; tile < 16; ++tile) {
        const int p0 = tile << 9;
        #pragma unroll
        for (int c = 0; c < 4; ++c)
            for (int j = t; j < 512; j += 256)
                xs[c][j] = xb[c * LL + p0 + j];
        __syncthreads();

        // c0 (BN+ReLU of 1x1 conv), transposed into LDS
        for (int i = t; i < 8192; i += 256) {
            int l = i >> 4, u = i & 15;
            float s = bf1[u];
            #pragma unroll
            for (int c = 0; c < 4; ++c) s += wf1[u][c] * xs[c][l];
            c0t[l][u] = fmaxf(s, 0.f);
        }
        __syncthreads();

        // Gram accumulation: thread quad (cg,dg) owns 8x8 block, strided l
        #pragma unroll
        for (int i = 0; i < 8; ++i) {
            int l = g + (i << 6);
            const float* row = &c0t[l][0];
            float4 a0 = ld4(row + cg * 8), a1 = ld4(row + cg * 8 + 4);
            float4 b0 = ld4(row + dg * 8), b1 = ld4(row + dg * 8 + 4);
            float av[8] = {a0.x, a0.y, a0.z, a0.w, a1.x, a1.y, a1.z, a1.w};
            float bv[8] = {b0.x, b0.y, b0.z, b0.w, b1.x, b1.y, b1.z, b1.w};
            #pragma unroll
            for (int ii = 0; ii < 8; ++ii)
                #pragma unroll
                for (int jj = 0; jj < 8; ++jj) acc[ii][jj] += av[ii] * bv[jj];
        }
        __syncthreads();
    }

    // reduce over g: butterfly over lane bits 2..5 (16 g-values per wave)
    #pragma unroll
    for (int m = 4; m <= 32; m <<= 1)
        #pragma unroll
        for (int ii = 0; ii < 8; ++ii)
            #pragma unroll
            for (int jj = 0; jj < 8; ++jj)
                acc[ii][jj] += __shfl_xor(acc[ii][jj], m, 64);

    const int wv = t >> 6, lane = t & 63;
    if (lane < 4) {
        #pragma unroll
        for (int ii = 0; ii < 8; ++ii)
            #pragma unroll
            for (int jj = 0; jj < 8; ++jj)
                part[wv][lane][ii * 8 + jj] = acc[ii][jj];
    }
    __syncthreads();
    {
        int qq = t >> 6, ii = (t >> 3) & 7, jj = t & 7;
        float s = part[0][qq][ii * 8 + jj] + part[1][qq][ii * 8 + jj]
                + part[2][qq][ii * 8 + jj] + part[3][qq][ii * 8 + jj];
        gram[(qq >> 1) * 8 + ii][(qq & 1) * 8 + jj] = s;
    }
    __syncthreads();

    // softmax(max_d(row) - gram) over d, scaled by beta
    {
        const float beta = beta_cam[0];
        int c = t >> 4, d = t & 15;  (void)c;
        float gv = gram[t >> 4][d];
        float rm = gv;
        #pragma unroll
        for (int m = 1; m < 16; m <<= 1) rm = fmaxf(rm, __shfl_xor(rm, m, 64));
        float a = rm - gv;
        float am = a;
        #pragma unroll
        for (int m = 1; m < 16; m <<= 1) am = fmaxf(am, __shfl_xor(am, m, 64));
        float e = __expf(a - am);
        float ssum = e;
        #pragma unroll
        for (int m = 1; m < 16; m <<= 1) ssum += __shfl_xor(ssum, m, 64);
        attn[t >> 4][d] = beta * e / ssum;
    }
    __syncthreads();

    // M[o][u] = inv2[o] * (wc2[o][u] + sum_d wc2[o][d] * A'[d][u])
    {
        int o = t >> 4, u = t & 15;
        float inv2 = g2[o] * rsqrtf(v2[o] + 1e-5f);
        float s = wc2[o * 16 + u];
        #pragma unroll
        for (int d = 0; d < 16; ++d) s += wc2[o * 16 + d] * attn[d][u];
        Mout[b * 256 + t] = s * inv2;
    }
}

// ---------------------------------------------------------------------------
// Kernel B: fea0 (K=32 conv) staged in LDS, then per-thread 4 positions:
// conv_fusion (fea1 + dilated fea2) + c2 = relu(M*c0 + bf2); float4 store.
// grid = 256 batches * 8 tiles of 1024, block = 256
// ---------------------------------------------------------------------------
__global__ __launch_bounds__(256) void kernB(
    const float* __restrict__ x,
    const float* __restrict__ w00, const float* __restrict__ b00,
    const float* __restrict__ w01, const float* __restrict__ b01,
    const float* __restrict__ w02, const float* __restrict__ b02,
    const float* __restrict__ wc1, const float* __restrict__ g1,
    const float* __restrict__ bt1, const float* __restrict__ m1,
    const float* __restrict__ v1,
    const float* __restrict__ g2, const float* __restrict__ bt2,
    const float* __restrict__ m2, const float* __restrict__ v2,
    const float* __restrict__ Min, float* __restrict__ out)
{
    __shared__ float xs[4][1092];   // x[p0-32 .. p0+1060)
    __shared__ float f0[8][1060];   // fea0[p0-16 .. p0+1044)
    __shared__ float Ms[16][16];
    __shared__ float wf1s[16][4];
    __shared__ float bf1s[16];
    __shared__ float bf2s[16];

    const int blk = blockIdx.x;
    const int b = blk >> 3;
    const int p0 = (blk & 7) << 10;
    const int t = threadIdx.x;
    const float* xb = x + (size_t)b * 4 * LL;

    if (t < 16) {
        float inv1 = g1[t] * rsqrtf(v1[t] + 1e-5f);
        #pragma unroll
        for (int c = 0; c < 4; ++c) wf1s[t][c] = wc1[t * 4 + c] * inv1;
        bf1s[t] = bt1[t] - m1[t] * inv1;
        float inv2 = g2[t] * rsqrtf(v2[t] + 1e-5f);
        bf2s[t] = bt2[t] - m2[t] * inv2;
    }
    Ms[t >> 4][t & 15] = Min[b * 256 + t];

    #pragma unroll
    for (int c = 0; c < 4; ++c)
        for (int j = t; j < 1092; j += 256) {
            int xp = p0 - 32 + j;
            xs[c][j] = (xp >= 0 && xp < LL) ? xb[c * LL + xp] : 0.f;
        }
    __syncthreads();

    // fea0: groups of 4 positions, all 8 out-channels per thread
    for (int gi = t; gi < 265; gi += 256) {
        const int ps = p0 - 16 + (gi << 2);
        float a[8][4];
        #pragma unroll
        for (int o = 0; o < 8; ++o)
            #pragma unroll
            for (int p = 0; p < 4; ++p) a[o][p] = 0.f;
        #pragma unroll
        for (int c = 0; c < 4; ++c) {
            float f[36];
            #pragma unroll
            for (int ii = 0; ii < 9; ++ii) {
                float4 v = ld4(&xs[c][(gi << 2) + (ii << 2)]);
                f[ii * 4 + 0] = v.x; f[ii * 4 + 1] = v.y;
                f[ii * 4 + 2] = v.z; f[ii * 4 + 3] = v.w;
            }
            #pragma unroll
            for (int k = 0; k < 32; ++k)
                #pragma unroll
                for (int o = 0; o < 8; ++o) {
                    float w = w00[o * 128 + c * 32 + k];   // uniform -> s_load
                    #pragma unroll
                    for (int p = 0; p < 4; ++p) a[o][p] += w * f[k + p];
                }
        }
        #pragma unroll
        for (int o = 0; o < 8; ++o)
            #pragma unroll
            for (int p = 0; p < 4; ++p) {
                int pp = ps + p;
                f0[o][(gi << 2) + p] =
                    (pp >= 0 && pp < LL + 1) ? a[o][p] + b00[o] : 0.f;
            }
    }
    __syncthreads();

    const int l0 = p0 + (t << 2);

    // conv_fusion: fea1 (taps f[9+p+k]) and fea2 dil=2 (taps f[2+p+2k])
    float acc[16][4];
    #pragma unroll
    for (int o = 0; o < 8; ++o) {
        float bb1 = b01[o], bb2 = b02[o];
        #pragma unroll
        for (int p = 0; p < 4; ++p) { acc[o][p] = bb1; acc[8 + o][p] = bb2; }
    }
    for (int oc = 0; oc < 8; ++oc) {
        float f[40];
        #pragma unroll
        for (int ii = 0; ii < 10; ++ii) {
            float4 v = ld4(&f0[oc][(t << 2) + (ii << 2)]);
            f[ii * 4 + 0] = v.x; f[ii * 4 + 1] = v.y;
            f[ii * 4 + 2] = v.z; f[ii * 4 + 3] = v.w;
        }
        #pragma unroll
        for (int k = 0; k < 16; ++k)
            #pragma unroll
            for (int o = 0; o < 8; ++o) {
                float w1 = w01[o * 128 + oc * 16 + k];   // uniform -> s_load
                float w2 = w02[o * 128 + oc * 16 + k];
                #pragma unroll
                for (int p = 0; p < 4; ++p) {
                    acc[o][p]     += w1 * f[9 + p + k];
                    acc[8 + o][p] += w2 * f[2 + p + 2 * k];
                }
            }
    }
    // fea2 zero-pad positions: l == 0, l >= 8190
    #pragma unroll
    for (int p = 0; p < 4; ++p) {
        int l = l0 + p;
        if (l < 1 || l > LL - 3) {
            #pragma unroll
            for (int o = 0; o < 8; ++o) acc[8 + o][p] = 0.f;
        }
    }

    // c0 for the 4 positions
    float xv[4][4];
    #pragma unroll
    for (int c = 0; c < 4; ++c) {
        float4 v = ld4(&xs[c][(t << 2) + 32]);
        xv[c][0] = v.x; xv[c][1] = v.y; xv[c][2] = v.z; xv[c][3] = v.w;
    }
    float c0v[16][4];
    #pragma unroll
    for (int u = 0; u < 16; ++u) {
        float w0 = wf1s[u][0], w1 = wf1s[u][1], w2 = wf1s[u][2], w3 = wf1s[u][3];
        float bb = bf1s[u];
        #pragma unroll
        for (int p = 0; p < 4; ++p) {
            float s = bb + w0 * xv[0][p] + w1 * xv[1][p]
                         + w2 * xv[2][p] + w3 * xv[3][p];
            c0v[u][p] = fmaxf(s, 0.f);
        }
    }

    // c2 = relu(M * c0 + bf2); out = conv_fusion + c2
    float* ob = out + ((size_t)b * 16) * LL;
    #pragma unroll
    for (int o = 0; o < 16; ++o) {
        float t0 = bf2s[o], t1 = bf2s[o], t2 = bf2s[o], t3 = bf2s[o];
        #pragma unroll
        for (int u = 0; u < 16; ++u) {
            float m = Ms[o][u];
            t0 += m * c0v[u][0]; t1 += m * c0v[u][1];
            t2 += m * c0v[u][2]; t3 += m * c0v[u][3];
        }
        float4 r;
        r.x = acc[o][0] + fmaxf(t0, 0.f);
        r.y = acc[o][1] + fmaxf(t1, 0.f);
        r.z = acc[o][2] + fmaxf(t2, 0.f);
        r.w = acc[o][3] + fmaxf(t3, 0.f);
        *reinterpret_cast<float4*>(&ob[o * LL + l0]) = r;
    }
}

extern "C" void kernel_launch(void* const* d_in, const int* in_sizes, int n_in,
                              void* d_out, int out_size, void* d_ws, size_t ws_size,
                              hipStream_t stream)
{
    const float* x    = (const float*)d_in[0];
    const float* w00  = (const float*)d_in[1];
    const float* b00  = (const float*)d_in[2];
    const float* w01  = (const float*)d_in[3];
    const float* b01  = (const float*)d_in[4];
    const float* w02  = (const float*)d_in[5];
    const float* b02  = (const float*)d_in[6];
    const float* wc1  = (const float*)d_in[7];
    const float* g1   = (const float*)d_in[8];
    const float* bt1  = (const float*)d_in[9];
    const float* m1   = (const float*)d_in[10];
    const float* v1   = (const float*)d_in[11];
    const float* beta = (const float*)d_in[12];
    const float* wc2  = (const float*)d_in[13];
    const float* g2   = (const float*)d_in[14];
    const float* bt2  = (const float*)d_in[15];
    const float* m2   = (const float*)d_in[16];
    const float* v2   = (const float*)d_in[17];

    float* M = (float*)d_ws;
    float* o = (float*)d_out;

    hipLaunchKernelGGL(kernA, dim3(256), dim3(256), 0, stream,
        x, wc1, g1, bt1, m1, v1, beta, wc2, g2, bt2, m2, v2, M);
    hipLaunchKernelGGL(kernB, dim3(2048), dim3(256), 0, stream,
        x, w00, b00, w01, b01, w02, b02, wc1, g1, bt1, m1, v1,
        g2, bt2, m2, v2, M, o);
}

// Round 2
// 260.762 us; speedup vs baseline: 3.9811x; 3.9811x over previous
//
#include <hip/hip_runtime.h>

#define LL 8192
#define TT 512   // positions per block (kernB)

__device__ __forceinline__ float4 ld4(const float* p) {
    return *reinterpret_cast<const float4*>(p);
}
__device__ __forceinline__ float2 ld2(const float* p) {
    return *reinterpret_cast<const float2*>(p);
}

// ---------------------------------------------------------------------------
// Kernel A: per-batch channel attention -> fused matrix M = W2bn * (I + beta*A)
// grid = 256 (one block per batch), block = 256
// ---------------------------------------------------------------------------
__global__ __launch_bounds__(256) void kernA(
    const float* __restrict__ x, const float* __restrict__ wc1,
    const float* __restrict__ g1, const float* __restrict__ bt1,
    const float* __restrict__ m1, const float* __restrict__ v1,
    const float* __restrict__ beta_cam, const float* __restrict__ wc2,
    const float* __restrict__ g2, const float* __restrict__ bt2,
    const float* __restrict__ m2, const float* __restrict__ v2,
    float* __restrict__ Mout)
{
    __shared__ float xs[4][512];
    __shared__ float c0t[512][20];
    __shared__ float part[4][4][64];
    __shared__ float gram[16][16];
    __shared__ float attn[16][16];
    __shared__ float wf1[16][4];
    __shared__ float bf1[16];

    const int b = blockIdx.x;
    const int t = threadIdx.x;
    const float* xb = x + (size_t)b * 4 * LL;

    if (t < 16) {
        float inv = g1[t] * rsqrtf(v1[t] + 1e-5f);
        #pragma unroll
        for (int c = 0; c < 4; ++c) wf1[t][c] = wc1[t * 4 + c] * inv;
        bf1[t] = bt1[t] - m1[t] * inv;
    }
    __syncthreads();

    float acc[8][8];
    #pragma unroll
    for (int i = 0; i < 8; ++i)
        #pragma unroll
        for (int j = 0; j < 8; ++j) acc[i][j] = 0.f;

    const int q = t & 3, g = t >> 2;
    const int cg = q >> 1, dg = q & 1;

    for (int tile = 0; tile < 16; ++tile) {
        const int p0 = tile << 9;
        #pragma unroll
        for (int c = 0; c < 4; ++c)
            for (int j = t; j < 512; j += 256)
                xs[c][j] = xb[c * LL + p0 + j];
        __syncthreads();

        for (int i = t; i < 8192; i += 256) {
            int l = i >> 4, u = i & 15;
            float s = bf1[u];
            #pragma unroll
            for (int c = 0; c < 4; ++c) s += wf1[u][c] * xs[c][l];
            c0t[l][u] = fmaxf(s, 0.f);
        }
        __syncthreads();

        #pragma unroll
        for (int i = 0; i < 8; ++i) {
            int l = g + (i << 6);
            const float* row = &c0t[l][0];
            float4 a0 = ld4(row + cg * 8), a1 = ld4(row + cg * 8 + 4);
            float4 b0 = ld4(row + dg * 8), b1 = ld4(row + dg * 8 + 4);
            float av[8] = {a0.x, a0.y, a0.z, a0.w, a1.x, a1.y, a1.z, a1.w};
            float bv[8] = {b0.x, b0.y, b0.z, b0.w, b1.x, b1.y, b1.z, b1.w};
            #pragma unroll
            for (int ii = 0; ii < 8; ++ii)
                #pragma unroll
                for (int jj = 0; jj < 8; ++jj) acc[ii][jj] += av[ii] * bv[jj];
        }
        __syncthreads();
    }

    #pragma unroll
    for (int m = 4; m <= 32; m <<= 1)
        #pragma unroll
        for (int ii = 0; ii < 8; ++ii)
            #pragma unroll
            for (int jj = 0; jj < 8; ++jj)
                acc[ii][jj] += __shfl_xor(acc[ii][jj], m, 64);

    const int wv = t >> 6, lane = t & 63;
    if (lane < 4) {
        #pragma unroll
        for (int ii = 0; ii < 8; ++ii)
            #pragma unroll
            for (int jj = 0; jj < 8; ++jj)
                part[wv][lane][ii * 8 + jj] = acc[ii][jj];
    }
    __syncthreads();
    {
        int qq = t >> 6, ii = (t >> 3) & 7, jj = t & 7;
        float s = part[0][qq][ii * 8 + jj] + part[1][qq][ii * 8 + jj]
                + part[2][qq][ii * 8 + jj] + part[3][qq][ii * 8 + jj];
        gram[(qq >> 1) * 8 + ii][(qq & 1) * 8 + jj] = s;
    }
    __syncthreads();

    {
        const float beta = beta_cam[0];
        int d = t & 15;
        float gv = gram[t >> 4][d];
        float rm = gv;
        #pragma unroll
        for (int m = 1; m < 16; m <<= 1) rm = fmaxf(rm, __shfl_xor(rm, m, 64));
        float a = rm - gv;
        float am = a;
        #pragma unroll
        for (int m = 1; m < 16; m <<= 1) am = fmaxf(am, __shfl_xor(am, m, 64));
        float e = __expf(a - am);
        float ssum = e;
        #pragma unroll
        for (int m = 1; m < 16; m <<= 1) ssum += __shfl_xor(ssum, m, 64);
        attn[t >> 4][d] = beta * e / ssum;
    }
    __syncthreads();

    {
        int o = t >> 4, u = t & 15;
        float inv2 = g2[o] * rsqrtf(v2[o] + 1e-5f);
        float s = wc2[o * 16 + u];
        #pragma unroll
        for (int d = 0; d < 16; ++d) s += wc2[o * 16 + d] * attn[d][u];
        Mout[b * 256 + t] = s * inv2;
    }
}

// ---------------------------------------------------------------------------
// Kernel B: T=512 tile, 2 positions/thread, low-VGPR phase-separated.
// grid = 256 batches * 16 tiles, block = 256, 4 blocks/CU target.
// ---------------------------------------------------------------------------
__global__ __launch_bounds__(256, 4) void kernB(
    const float* __restrict__ x,
    const float* __restrict__ w00, const float* __restrict__ b00,
    const float* __restrict__ w01, const float* __restrict__ b01,
    const float* __restrict__ w02, const float* __restrict__ b02,
    const float* __restrict__ wc1, const float* __restrict__ g1,
    const float* __restrict__ bt1, const float* __restrict__ m1,
    const float* __restrict__ v1,
    const float* __restrict__ g2, const float* __restrict__ bt2,
    const float* __restrict__ m2, const float* __restrict__ v2,
    const float* __restrict__ Min, float* __restrict__ out)
{
    __shared__ float xs[4][584];    // x window [p0-32, p0+552)
    __shared__ float f0[8][548];    // fea0 slots s <-> index j = p0-16+s
    __shared__ float Mst[16][16];   // transposed: Mst[u][o]
    __shared__ float wf1s[16][4];
    __shared__ float bf1s[16];
    __shared__ float bf2s[16];

    const int blk = blockIdx.x;
    const int b  = blk >> 4;
    const int p0 = (blk & 15) << 9;
    const int t  = threadIdx.x;
    const float* xb = x + (size_t)b * 4 * LL;

    if (t < 16) {
        float inv1 = g1[t] * rsqrtf(v1[t] + 1e-5f);
        #pragma unroll
        for (int c = 0; c < 4; ++c) wf1s[t][c] = wc1[t * 4 + c] * inv1;
        bf1s[t] = bt1[t] - m1[t] * inv1;
        float inv2 = g2[t] * rsqrtf(v2[t] + 1e-5f);
        bf2s[t] = bt2[t] - m2[t] * inv2;
    }
    Mst[t & 15][t >> 4] = Min[b * 256 + t];

    // ---- stage x window ----
    if (p0 >= 32 && p0 + 552 <= LL) {          // interior tiles: fast path
        if (t < 146) {
            const float* src = xb + p0 - 32 + (t << 2);
            #pragma unroll
            for (int c = 0; c < 4; ++c)
                *reinterpret_cast<float4*>(&xs[c][t << 2]) = ld4(src + c * LL);
        }
    } else {
        for (int i = t; i < 584; i += 256) {
            int xp = p0 - 32 + i;
            bool ok = (xp >= 0 && xp < LL);
            #pragma unroll
            for (int c = 0; c < 4; ++c)
                xs[c][i] = ok ? xb[c * LL + xp] : 0.f;
        }
    }
    __syncthreads();

    // ---- fea0: 137 groups of 4 slots, single pass ----
    if (t < 137) {
        const int s0 = t << 2;
        float a[8][4];
        #pragma unroll
        for (int o = 0; o < 8; ++o)
            #pragma unroll
            for (int p = 0; p < 4; ++p) a[o][p] = 0.f;

        #pragma unroll 1
        for (int c = 0; c < 4; ++c) {
            float f[36];
            #pragma unroll
            for (int ii = 0; ii < 9; ++ii) {
                float4 v = ld4(&xs[c][s0 + (ii << 2)]);
                f[ii * 4 + 0] = v.x; f[ii * 4 + 1] = v.y;
                f[ii * 4 + 2] = v.z; f[ii * 4 + 3] = v.w;
            }
            #pragma unroll
            for (int k = 0; k < 32; ++k)
                #pragma unroll
                for (int o = 0; o < 8; ++o) {
                    float w = w00[o * 128 + c * 32 + k];
                    #pragma unroll
                    for (int p = 0; p < 4; ++p) a[o][p] += w * f[k + p];
                }
        }
        #pragma unroll
        for (int o = 0; o < 8; ++o) {
            float4 r;
            float bb = b00[o];
            int j0 = p0 - 16 + s0;
            r.x = (j0 + 0 >= 0 && j0 + 0 <= LL) ? a[o][0] + bb : 0.f;
            r.y = (j0 + 1 >= 0 && j0 + 1 <= LL) ? a[o][1] + bb : 0.f;
            r.z = (j0 + 2 >= 0 && j0 + 2 <= LL) ? a[o][2] + bb : 0.f;
            r.w = (j0 + 3 >= 0 && j0 + 3 <= LL) ? a[o][3] + bb : 0.f;
            *reinterpret_cast<float4*>(&f0[o][s0]) = r;
        }
    }
    __syncthreads();

    const int l0 = p0 + (t << 1);

    // ---- conv fusion: fea1 taps f[7+k+p], fea2 taps f[2k+p] ----
    float acc[16][2];
    #pragma unroll
    for (int o = 0; o < 8; ++o) {
        float bb1 = b01[o], bb2 = b02[o];
        acc[o][0] = bb1;     acc[o][1] = bb1;
        acc[8 + o][0] = bb2; acc[8 + o][1] = bb2;
    }
    #pragma unroll 1
    for (int oc = 0; oc < 8; ++oc) {
        float f[32];                       // f0[oc][2t+2 .. 2t+33]
        const float* base = &f0[oc][(t << 1) + 2];
        #pragma unroll
        for (int ii = 0; ii < 16; ++ii) {
            float2 v = ld2(base + (ii << 1));
            f[ii * 2] = v.x; f[ii * 2 + 1] = v.y;
        }
        #pragma unroll
        for (int k = 0; k < 16; ++k)
            #pragma unroll
            for (int o = 0; o < 8; ++o) {
                float w1 = w01[o * 128 + oc * 16 + k];
                float w2 = w02[o * 128 + oc * 16 + k];
                acc[o][0]     += w1 * f[7 + k];
                acc[o][1]     += w1 * f[8 + k];
                acc[8 + o][0] += w2 * f[2 * k];
                acc[8 + o][1] += w2 * f[2 * k + 1];
            }
    }
    // fea2 zero-pad positions: l < 1 or l > 8189
    #pragma unroll
    for (int p = 0; p < 2; ++p) {
        int l = l0 + p;
        if (l < 1 || l > LL - 3) {
            #pragma unroll
            for (int o = 0; o < 8; ++o) acc[8 + o][p] = 0.f;
        }
    }

    // ---- c0 (recomputed per u) + c2 = relu(M*c0 + bf2) ----
    float xv[4][2];
    #pragma unroll
    for (int c = 0; c < 4; ++c) {
        float2 v = ld2(&xs[c][(t << 1) + 32]);
        xv[c][0] = v.x; xv[c][1] = v.y;
    }
    float c2a[16][2];
    #pragma unroll
    for (int o = 0; o < 16; ++o) { c2a[o][0] = bf2s[o]; c2a[o][1] = bf2s[o]; }

    #pragma unroll 1
    for (int u = 0; u < 16; ++u) {
        float4 wf = ld4(&wf1s[u][0]);
        float bb = bf1s[u];
        float c00 = fmaxf(bb + wf.x * xv[0][0] + wf.y * xv[1][0]
                             + wf.z * xv[2][0] + wf.w * xv[3][0], 0.f);
        float c01 = fmaxf(bb + wf.x * xv[0][1] + wf.y * xv[1][1]
                             + wf.z * xv[2][1] + wf.w * xv[3][1], 0.f);
        const float* mrow = &Mst[u][0];
        #pragma unroll
        for (int og = 0; og < 4; ++og) {
            float4 m = ld4(mrow + (og << 2));
            c2a[og * 4 + 0][0] += m.x * c00; c2a[og * 4 + 0][1] += m.x * c01;
            c2a[og * 4 + 1][0] += m.y * c00; c2a[og * 4 + 1][1] += m.y * c01;
            c2a[og * 4 + 2][0] += m.z * c00; c2a[og * 4 + 2][1] += m.z * c01;
            c2a[og * 4 + 3][0] += m.w * c00; c2a[og * 4 + 3][1] += m.w * c01;
        }
    }

    // ---- combine + store ----
    float* ob = out + (size_t)b * 16 * LL + l0;
    #pragma unroll
    for (int o = 0; o < 16; ++o) {
        float2 r;
        r.x = acc[o][0] + fmaxf(c2a[o][0], 0.f);
        r.y = acc[o][1] + fmaxf(c2a[o][1], 0.f);
        *reinterpret_cast<float2*>(ob + o * LL) = r;
    }
}

extern "C" void kernel_launch(void* const* d_in, const int* in_sizes, int n_in,
                              void* d_out, int out_size, void* d_ws, size_t ws_size,
                              hipStream_t stream)
{
    const float* x    = (const float*)d_in[0];
    const float* w00  = (const float*)d_in[1];
    const float* b00  = (const float*)d_in[2];
    const float* w01  = (const float*)d_in[3];
    const float* b01  = (const float*)d_in[4];
    const float* w02  = (const float*)d_in[5];
    const float* b02  = (const float*)d_in[6];
    const float* wc1  = (const float*)d_in[7];
    const float* g1   = (const float*)d_in[8];
    const float* bt1  = (const float*)d_in[9];
    const float* m1   = (const float*)d_in[10];
    const float* v1   = (const float*)d_in[11];
    const float* beta = (const float*)d_in[12];
    const float* wc2  = (const float*)d_in[13];
    const float* g2   = (const float*)d_in[14];
    const float* bt2  = (const float*)d_in[15];
    const float* m2   = (const float*)d_in[16];
    const float* v2   = (const float*)d_in[17];

    float* M = (float*)d_ws;
    float* o = (float*)d_out;

    hipLaunchKernelGGL(kernA, dim3(256), dim3(256), 0, stream,
        x, wc1, g1, bt1, m1, v1, beta, wc2, g2, bt2, m2, v2, M);
    hipLaunchKernelGGL(kernB, dim3(256 * 16), dim3(256), 0, stream,
        x, w00, b00, w01, b01, w02, b02, wc1, g1, bt1, m1, v1,
        g2, bt2, m2, v2, M, o);
}

// Round 3
// 128.042 us; speedup vs baseline: 8.1076x; 2.0365x over previous
//
#include <hip/hip_runtime.h>

#define LL 8192

typedef __attribute__((ext_vector_type(8))) short bf16x8;
typedef __attribute__((ext_vector_type(4))) float f32x4;

union U4 { uint4 u; bf16x8 v; };

__device__ __forceinline__ float4 ld4(const float* p) {
    return *reinterpret_cast<const float4*>(p);
}
__device__ __forceinline__ unsigned short f2bf(float f) {
    union { float f; unsigned u; } v; v.f = f;
    unsigned r = v.u + 0x7fffu + ((v.u >> 16) & 1u);
    return (unsigned short)(r >> 16);
}
__device__ __forceinline__ unsigned cvt_pk_bf16(float lo, float hi) {
    unsigned r;
    asm("v_cvt_pk_bf16_f32 %0, %1, %2" : "=v"(r) : "v"(lo), "v"(hi));
    return r;
}
__device__ __forceinline__ float bf2f_lo(unsigned u) {
    union { unsigned u; float f; } v; v.u = u << 16; return v.f;
}
__device__ __forceinline__ float bf2f_hi(unsigned u) {
    union { unsigned u; float f; } v; v.u = u & 0xffff0000u; return v.f;
}

// ---------------------------------------------------------------------------
// kernW: pack conv weights into MFMA A-fragment lane order (bf16).
// wA0: fea0 (w00), chunks c=0..7 over taps kt=4c+(l>>4), rows o (8 real), ch j (4 real)
// wA1: fusion (w01 + dilated w02), q = 4c+(l>>4), r = q-14; fea1: q=kt+7; fea2: q=2kt
// grid 1 x 512
// ---------------------------------------------------------------------------
__global__ __launch_bounds__(512) void kernW(
    const float* __restrict__ w00, const float* __restrict__ w01,
    const float* __restrict__ w02,
    unsigned short* __restrict__ wA0, unsigned short* __restrict__ wA1)
{
    const int i = threadIdx.x;        // 0..511
    const int c = i >> 6, l = i & 63;
    const int o = l & 15, g = l >> 4;
    {
        int kt = 4 * c + g;           // 0..31
        #pragma unroll
        for (int j = 0; j < 8; ++j) {
            float v = (o < 8 && j < 4) ? w00[(o * 4 + j) * 32 + kt] : 0.f;
            wA0[(c * 64 + l) * 8 + j] = f2bf(v);
        }
    }
    {
        int q = 4 * c + g;            // 0..31
        #pragma unroll
        for (int j = 0; j < 8; ++j) {
            float v = 0.f;
            if (o < 8) {
                if (q >= 7 && q <= 22) v = w01[(o * 8 + j) * 16 + (q - 7)];
            } else {
                if (!(q & 1) && q <= 30) v = w02[((o - 8) * 8 + j) * 16 + (q >> 1)];
            }
            wA1[(c * 64 + l) * 8 + j] = f2bf(v);
        }
    }
}

// ---------------------------------------------------------------------------
// kernA1: partial Gram of c0 over a 2048-position chunk. grid 256*4, block 256
// ---------------------------------------------------------------------------
__global__ __launch_bounds__(256) void kernA1(
    const float* __restrict__ x, const float* __restrict__ wc1,
    const float* __restrict__ g1, const float* __restrict__ bt1,
    const float* __restrict__ m1, const float* __restrict__ v1,
    float* __restrict__ partial)
{
    __shared__ float xs[4][512];
    __shared__ float c0t[512][20];
    __shared__ float part[4][4][64];
    __shared__ float wf1[16][4];
    __shared__ float bf1[16];

    const int blk = blockIdx.x;
    const int b = blk >> 2, chunk = blk & 3;
    const int t = threadIdx.x;
    const float* xb = x + (size_t)b * 4 * LL;

    if (t < 16) {
        float inv = g1[t] * rsqrtf(v1[t] + 1e-5f);
        #pragma unroll
        for (int c = 0; c < 4; ++c) wf1[t][c] = wc1[t * 4 + c] * inv;
        bf1[t] = bt1[t] - m1[t] * inv;
    }
    __syncthreads();

    float acc[8][8];
    #pragma unroll
    for (int i = 0; i < 8; ++i)
        #pragma unroll
        for (int j = 0; j < 8; ++j) acc[i][j] = 0.f;

    const int q = t & 3, g = t >> 2;
    const int cg = q >> 1, dg = q & 1;

    for (int tile = 0; tile < 4; ++tile) {
        const int p0 = (chunk * 4 + tile) << 9;
        #pragma unroll
        for (int c = 0; c < 4; ++c)
            for (int j = t; j < 512; j += 256)
                xs[c][j] = xb[c * LL + p0 + j];
        __syncthreads();

        for (int i = t; i < 8192; i += 256) {
            int ll = i >> 4, u = i & 15;
            float s = bf1[u];
            #pragma unroll
            for (int c = 0; c < 4; ++c) s += wf1[u][c] * xs[c][ll];
            c0t[ll][u] = fmaxf(s, 0.f);
        }
        __syncthreads();

        #pragma unroll
        for (int i = 0; i < 8; ++i) {
            int ll = g + (i << 6);
            const float* row = &c0t[ll][0];
            float4 a0 = ld4(row + cg * 8), a1 = ld4(row + cg * 8 + 4);
            float4 b0 = ld4(row + dg * 8), b1 = ld4(row + dg * 8 + 4);
            float av[8] = {a0.x, a0.y, a0.z, a0.w, a1.x, a1.y, a1.z, a1.w};
            float bv[8] = {b0.x, b0.y, b0.z, b0.w, b1.x, b1.y, b1.z, b1.w};
            #pragma unroll
            for (int ii = 0; ii < 8; ++ii)
                #pragma unroll
                for (int jj = 0; jj < 8; ++jj) acc[ii][jj] += av[ii] * bv[jj];
        }
        __syncthreads();
    }

    #pragma unroll
    for (int m = 4; m <= 32; m <<= 1)
        #pragma unroll
        for (int ii = 0; ii < 8; ++ii)
            #pragma unroll
            for (int jj = 0; jj < 8; ++jj)
                acc[ii][jj] += __shfl_xor(acc[ii][jj], m, 64);

    const int wv = t >> 6, lane = t & 63;
    if (lane < 4) {
        #pragma unroll
        for (int ii = 0; ii < 8; ++ii)
            #pragma unroll
            for (int jj = 0; jj < 8; ++jj)
                part[wv][lane][ii * 8 + jj] = acc[ii][jj];
    }
    __syncthreads();
    {
        int qq = t >> 6, ii = (t >> 3) & 7, jj = t & 7;
        float s = part[0][qq][ii * 8 + jj] + part[1][qq][ii * 8 + jj]
                + part[2][qq][ii * 8 + jj] + part[3][qq][ii * 8 + jj];
        partial[(size_t)(b * 4 + chunk) * 256 + t] = s;
    }
}

// ---------------------------------------------------------------------------
// kernA2: reduce partials -> softmax -> M -> Mp (bf16 A-frag order). grid 256
// ---------------------------------------------------------------------------
__global__ __launch_bounds__(256) void kernA2(
    const float* __restrict__ partial, const float* __restrict__ beta_cam,
    const float* __restrict__ wc2, const float* __restrict__ g2,
    const float* __restrict__ bt2, const float* __restrict__ m2,
    const float* __restrict__ v2, unsigned short* __restrict__ Mp)
{
    __shared__ float gram[16][16];
    __shared__ float attn[16][16];
    __shared__ float Msh[16][16];
    const int b = blockIdx.x, t = threadIdx.x;
    const float* P = partial + (size_t)b * 1024;
    float s = P[t] + P[256 + t] + P[512 + t] + P[768 + t];
    {
        int qq = t >> 6, ii = (t >> 3) & 7, jj = t & 7;
        gram[(qq >> 1) * 8 + ii][(qq & 1) * 8 + jj] = s;
    }
    __syncthreads();
    {
        const float beta = beta_cam[0];
        int d = t & 15;
        float gv = gram[t >> 4][d];
        float rm = gv;
        #pragma unroll
        for (int m = 1; m < 16; m <<= 1) rm = fmaxf(rm, __shfl_xor(rm, m, 64));
        float a = rm - gv;
        float am = a;
        #pragma unroll
        for (int m = 1; m < 16; m <<= 1) am = fmaxf(am, __shfl_xor(am, m, 64));
        float e = __expf(a - am);
        float ssum = e;
        #pragma unroll
        for (int m = 1; m < 16; m <<= 1) ssum += __shfl_xor(ssum, m, 64);
        attn[t >> 4][d] = beta * e / ssum;
    }
    __syncthreads();
    {
        int o = t >> 4, u = t & 15;
        float inv2 = g2[o] * rsqrtf(v2[o] + 1e-5f);
        float sm = wc2[o * 16 + u];
        #pragma unroll
        for (int d = 0; d < 16; ++d) sm += wc2[o * 16 + d] * attn[d][u];
        Msh[o][u] = sm * inv2;
    }
    __syncthreads();
    for (int idx = t; idx < 512; idx += 256) {
        int l = idx >> 3, j = idx & 7;
        int k = 8 * (l >> 4) + j, o = l & 15;
        float v = (k < 16) ? Msh[o][k] : 0.f;
        Mp[(size_t)b * 512 + idx] = f2bf(v);
    }
}

// ---------------------------------------------------------------------------
// kernB: MFMA conv pipeline. grid 256*16, block 256 (4 waves), T=512 pos.
// phase1: fea0 = w00 (*) x  -> f0T LDS (bf16, [pos][8ch] 16B rows)
// phase2: fusion = wA1 (*) fea0  + c2 = relu(M c0 + bf2), store f32
// ---------------------------------------------------------------------------
__global__ __launch_bounds__(256, 3) void kernB(
    const float* __restrict__ x,
    const float* __restrict__ b00, const float* __restrict__ b01,
    const float* __restrict__ b02,
    const float* __restrict__ wc1, const float* __restrict__ g1,
    const float* __restrict__ bt1, const float* __restrict__ m1,
    const float* __restrict__ v1,
    const float* __restrict__ g2, const float* __restrict__ bt2,
    const float* __restrict__ m2, const float* __restrict__ v2,
    const unsigned short* __restrict__ wA0, const unsigned short* __restrict__ wA1,
    const unsigned short* __restrict__ Mp, float* __restrict__ out)
{
    __shared__ __align__(16) unsigned short xT[592][8];   // x[p0-32 .. p0+560): [4ch|4 zero]
    __shared__ __align__(16) unsigned short f0T[560][8];  // fea0 slot s <-> j = p0-16+s

    const int blk = blockIdx.x;
    const int b  = blk >> 4;
    const int p0 = (blk & 15) << 9;
    const int t  = threadIdx.x;
    const int w  = t >> 6, l = t & 63;
    const int lane15 = l & 15, g = l >> 4;
    const float* xb = x + (size_t)b * 4 * LL;

    // ---- stage xT (bf16, zero outside [0,8192)) ----
    for (int i = t; i < 592; i += 256) {
        int xp = p0 - 32 + i;
        bool ok = (unsigned)xp < 8192u;
        float v0 = ok ? xb[0 * LL + xp] : 0.f;
        float v1_ = ok ? xb[1 * LL + xp] : 0.f;
        float v2_ = ok ? xb[2 * LL + xp] : 0.f;
        float v3_ = ok ? xb[3 * LL + xp] : 0.f;
        uint4 r;
        r.x = cvt_pk_bf16(v0, v1_);
        r.y = cvt_pk_bf16(v2_, v3_);
        r.z = 0u; r.w = 0u;
        *reinterpret_cast<uint4*>(&xT[i][0]) = r;
    }

    // preload phase-1 weights + bias
    bf16x8 a0[8];
    #pragma unroll
    for (int c = 0; c < 8; ++c)
        a0[c] = reinterpret_cast<const bf16x8*>(wA0)[c * 64 + l];
    float b00c[4];
    #pragma unroll
    for (int i = 0; i < 4; ++i) b00c[i] = b00[(4 * g + i) & 7];

    __syncthreads();

    // ---- phase 1: fea0 via MFMA, sliding B-window ----
    {
        int gj   = (w == 0) ? 0 : (w == 1) ? 9 : (w == 2) ? 18 : 27;
        int gend = gj + ((w == 3) ? 8 : 9);
        const int rb = lane15 + g;
        bf16x8 bb[8];
        {
            int base = 16 * gj + rb;
            #pragma unroll
            for (int c = 0; c < 8; ++c)
                bb[c] = *reinterpret_cast<const bf16x8*>(&xT[base + 4 * c][0]);
        }
        while (true) {
            f32x4 d = {0.f, 0.f, 0.f, 0.f};
            #pragma unroll
            for (int c = 0; c < 8; ++c)
                d = __builtin_amdgcn_mfma_f32_16x16x32_bf16(a0[c], bb[c], d, 0, 0, 0);
            if (g < 2) {
                int s = 16 * gj + lane15;
                int j = p0 - 16 + s;
                bool ok = (unsigned)j <= 8192u;
                float e0 = ok ? d[0] + b00c[0] : 0.f;
                float e1 = ok ? d[1] + b00c[1] : 0.f;
                float e2 = ok ? d[2] + b00c[2] : 0.f;
                float e3 = ok ? d[3] + b00c[3] : 0.f;
                uint2 wv;
                wv.x = cvt_pk_bf16(e0, e1);
                wv.y = cvt_pk_bf16(e2, e3);
                *reinterpret_cast<uint2*>(&f0T[s][4 * g]) = wv;
            }
            ++gj;
            if (gj >= gend) break;
            #pragma unroll
            for (int c = 0; c < 4; ++c) bb[c] = bb[c + 4];
            int base = 16 * gj + rb;
            #pragma unroll
            for (int c = 4; c < 8; ++c)
                bb[c] = *reinterpret_cast<const bf16x8*>(&xT[base + 4 * c][0]);
        }
    }

    // preload phase-2 constants
    bf16x8 a1[8];
    #pragma unroll
    for (int c = 0; c < 8; ++c)
        a1[c] = reinterpret_cast<const bf16x8*>(wA1)[c * 64 + l];
    bf16x8 mfrag = reinterpret_cast<const bf16x8*>(Mp)[b * 64 + l];
    float wfv[8][4], bf1v[8];
    #pragma unroll
    for (int j = 0; j < 8; ++j) {
        int u = (8 * g + j) & 15;
        float inv = g1[u] * rsqrtf(v1[u] + 1e-5f);
        #pragma unroll
        for (int c = 0; c < 4; ++c) wfv[j][c] = wc1[u * 4 + c] * inv;
        bf1v[j] = bt1[u] - m1[u] * inv;
    }
    float cb1[4], bf2v[4];
    #pragma unroll
    for (int i = 0; i < 4; ++i) {
        int o = 4 * g + i;
        cb1[i] = (o < 8) ? b01[o] : b02[o - 8];
        float inv2 = g2[o] * rsqrtf(v2[o] + 1e-5f);
        bf2v[i] = bt2[o] - m2[o] * inv2;
    }

    __syncthreads();

    // ---- phase 2: fusion + c2 + store ----
    {
        int gi = 8 * w;
        const int gend = gi + 8;
        const int rb = lane15 + g + 2;
        bf16x8 bb[8];
        {
            int base = 16 * gi + rb;
            #pragma unroll
            for (int c = 0; c < 8; ++c)
                bb[c] = *reinterpret_cast<const bf16x8*>(&f0T[base + 4 * c][0]);
        }
        float* ob = out + (size_t)b * 16 * LL;
        while (true) {
            f32x4 dF = {0.f, 0.f, 0.f, 0.f};
            #pragma unroll
            for (int c = 0; c < 8; ++c)
                dF = __builtin_amdgcn_mfma_f32_16x16x32_bf16(a1[c], bb[c], dF, 0, 0, 0);
            // c0 B-fragment (lanes g<2 own u = 8g+j)
            U4 uu; uu.u.x = 0u; uu.u.y = 0u; uu.u.z = 0u; uu.u.w = 0u;
            if (g < 2) {
                const uint2 xr = *reinterpret_cast<const uint2*>(&xT[32 + 16 * gi + lane15][0]);
                float xc0 = bf2f_lo(xr.x), xc1 = bf2f_hi(xr.x);
                float xc2 = bf2f_lo(xr.y), xc3 = bf2f_hi(xr.y);
                float cu[8];
                #pragma unroll
                for (int j = 0; j < 8; ++j)
                    cu[j] = fmaxf(bf1v[j] + wfv[j][0] * xc0 + wfv[j][1] * xc1
                                 + wfv[j][2] * xc2 + wfv[j][3] * xc3, 0.f);
                uu.u.x = cvt_pk_bf16(cu[0], cu[1]);
                uu.u.y = cvt_pk_bf16(cu[2], cu[3]);
                uu.u.z = cvt_pk_bf16(cu[4], cu[5]);
                uu.u.w = cvt_pk_bf16(cu[6], cu[7]);
            }
            f32x4 zc = {0.f, 0.f, 0.f, 0.f};
            f32x4 dC = __builtin_amdgcn_mfma_f32_16x16x32_bf16(mfrag, uu.v, zc, 0, 0, 0);

            const int p = p0 + 16 * gi + lane15;
            float* op = ob + p;
            #pragma unroll
            for (int i = 0; i < 4; ++i) {
                int o = 4 * g + i;
                float vf = dF[i] + cb1[i];
                if (o >= 8 && (p < 1 || p > LL - 3)) vf = 0.f;
                float c2 = fmaxf(dC[i] + bf2v[i], 0.f);
                op[(size_t)o * LL] = vf + c2;
            }
            ++gi;
            if (gi >= gend) break;
            #pragma unroll
            for (int c = 0; c < 4; ++c) bb[c] = bb[c + 4];
            int base = 16 * gi + rb;
            #pragma unroll
            for (int c = 4; c < 8; ++c)
                bb[c] = *reinterpret_cast<const bf16x8*>(&f0T[base + 4 * c][0]);
        }
    }
}

extern "C" void kernel_launch(void* const* d_in, const int* in_sizes, int n_in,
                              void* d_out, int out_size, void* d_ws, size_t ws_size,
                              hipStream_t stream)
{
    const float* x    = (const float*)d_in[0];
    const float* w00  = (const float*)d_in[1];
    const float* b00  = (const float*)d_in[2];
    const float* w01  = (const float*)d_in[3];
    const float* b01  = (const float*)d_in[4];
    const float* w02  = (const float*)d_in[5];
    const float* b02  = (const float*)d_in[6];
    const float* wc1  = (const float*)d_in[7];
    const float* g1   = (const float*)d_in[8];
    const float* bt1  = (const float*)d_in[9];
    const float* m1   = (const float*)d_in[10];
    const float* v1   = (const float*)d_in[11];
    const float* beta = (const float*)d_in[12];
    const float* wc2  = (const float*)d_in[13];
    const float* g2   = (const float*)d_in[14];
    const float* bt2  = (const float*)d_in[15];
    const float* m2   = (const float*)d_in[16];
    const float* v2   = (const float*)d_in[17];

    char* wsb = (char*)d_ws;
    float* partialp        = (float*)wsb;                         // 1,048,576 B
    unsigned short* Mpp    = (unsigned short*)(wsb + 1048576);    //   262,144 B
    unsigned short* wA0p   = (unsigned short*)(wsb + 1310720);    //     8,192 B
    unsigned short* wA1p   = (unsigned short*)(wsb + 1318912);    //     8,192 B
    float* o = (float*)d_out;

    hipLaunchKernelGGL(kernW, dim3(1), dim3(512), 0, stream, w00, w01, w02, wA0p, wA1p);
    hipLaunchKernelGGL(kernA1, dim3(1024), dim3(256), 0, stream,
        x, wc1, g1, bt1, m1, v1, partialp);
    hipLaunchKernelGGL(kernA2, dim3(256), dim3(256), 0, stream,
        partialp, beta, wc2, g2, bt2, m2, v2, Mpp);
    hipLaunchKernelGGL(kernB, dim3(4096), dim3(256), 0, stream,
        x, b00, b01, b02, wc1, g1, bt1, m1, v1, g2, bt2, m2, v2,
        wA0p, wA1p, Mpp, o);
}

// Round 4
// 95.693 us; speedup vs baseline: 10.8484x; 1.3381x over previous
//
#include <hip/hip_runtime.h>

#define LL 8192

typedef __attribute__((ext_vector_type(8))) short bf16x8;
typedef __attribute__((ext_vector_type(4))) float f32x4;

union U4 { uint4 u; bf16x8 v; };

__device__ __forceinline__ unsigned short f2bf(float f) {
    union { float f; unsigned u; } v; v.f = f;
    unsigned r = v.u + 0x7fffu + ((v.u >> 16) & 1u);
    return (unsigned short)(r >> 16);
}
__device__ __forceinline__ unsigned cvt_pk_bf16(float lo, float hi) {
    unsigned r;
    asm("v_cvt_pk_bf16_f32 %0, %1, %2" : "=v"(r) : "v"(lo), "v"(hi));
    return r;
}
__device__ __forceinline__ float bf2f_lo(unsigned u) {
    union { unsigned u; float f; } v; v.u = u << 16; return v.f;
}
__device__ __forceinline__ float bf2f_hi(unsigned u) {
    union { unsigned u; float f; } v; v.u = u & 0xffff0000u; return v.f;
}

// ---------------------------------------------------------------------------
// kernA1: Gram of c0 over a 1024-position chunk via MFMA (A-frag == B-frag).
// grid = 256*8, block = 256 (4 waves, each owns 256 positions = 8 K-chunks)
// ---------------------------------------------------------------------------
__global__ __launch_bounds__(256) void kernA1(
    const float* __restrict__ x, const float* __restrict__ wc1,
    const float* __restrict__ g1, const float* __restrict__ bt1,
    const float* __restrict__ m1, const float* __restrict__ v1,
    float* __restrict__ partial)
{
    __shared__ float xs[4][1024];                         // 16 KB (reused for gsum)
    __shared__ __align__(16) unsigned short c0f[16384];   // 32 KB frag-slot layout
    __shared__ float wf1[16][4];
    __shared__ float bf1[16];

    const int blk = blockIdx.x;
    const int b = blk >> 3, chunk = blk & 7;
    const int t = threadIdx.x;
    const int w = t >> 6, l = t & 63;
    const float* xb = x + (size_t)b * 4 * LL;
    const int p0 = chunk << 10;

    if (t < 16) {
        float inv = g1[t] * rsqrtf(v1[t] + 1e-5f);
        #pragma unroll
        for (int c = 0; c < 4; ++c) wf1[t][c] = wc1[t * 4 + c] * inv;
        bf1[t] = bt1[t] - m1[t] * inv;
    }
    // stage x chunk (coalesced)
    #pragma unroll
    for (int c = 0; c < 4; ++c)
        for (int j = t; j < 1024; j += 256)
            xs[c][j] = xb[c * LL + p0 + j];
    __syncthreads();

    // c0 -> bf16 frag-slot layout: slot = (p>>5)*64 + ((p>>3)&3)*16 + u, elem p&7
    {
        const int u = t & 15, pblk = t >> 4;
        float w0 = wf1[u][0], w1 = wf1[u][1], w2 = wf1[u][2], w3 = wf1[u][3];
        float bu = bf1[u];
        #pragma unroll 4
        for (int pp = 0; pp < 64; pp += 2) {
            int p = (pblk << 6) + pp;
            float c00 = fmaxf(bu + w0 * xs[0][p] + w1 * xs[1][p]
                                 + w2 * xs[2][p] + w3 * xs[3][p], 0.f);
            float c01 = fmaxf(bu + w0 * xs[0][p + 1] + w1 * xs[1][p + 1]
                                 + w2 * xs[2][p + 1] + w3 * xs[3][p + 1], 0.f);
            int slot = ((p >> 5) << 6) + (((p >> 3) & 3) << 4) + u;
            *reinterpret_cast<unsigned*>(&c0f[slot * 8 + (p & 7)]) =
                cvt_pk_bf16(c00, c01);
        }
    }
    __syncthreads();

    // Gram: wave w covers positions 256w..256w+255 -> 8 MFMAs, frag=one b128
    f32x4 acc = {0.f, 0.f, 0.f, 0.f};
    #pragma unroll
    for (int m = 0; m < 8; ++m) {
        int slot = (w * 8 + m) * 64 + l;
        bf16x8 fr = *reinterpret_cast<const bf16x8*>(&c0f[slot * 8]);
        acc = __builtin_amdgcn_mfma_f32_16x16x32_bf16(fr, fr, acc, 0, 0, 0);
    }

    // reduce 4 waves (gsum aliases xs)
    float* gsumf = &xs[0][0];
    {
        int col = l & 15, rg = l >> 4;
        #pragma unroll
        for (int i = 0; i < 4; ++i)
            gsumf[w * 256 + (rg * 4 + i) * 16 + col] = acc[i];
    }
    __syncthreads();
    partial[(size_t)(b * 8 + chunk) * 256 + t] =
        gsumf[t] + gsumf[256 + t] + gsumf[512 + t] + gsumf[768 + t];
}

// ---------------------------------------------------------------------------
// kernA2: reduce partials -> softmax -> M -> Mp; block 0 also packs weights.
// grid 256
// ---------------------------------------------------------------------------
__global__ __launch_bounds__(256) void kernA2(
    const float* __restrict__ partial, const float* __restrict__ beta_cam,
    const float* __restrict__ wc2, const float* __restrict__ g2,
    const float* __restrict__ bt2, const float* __restrict__ m2,
    const float* __restrict__ v2,
    const float* __restrict__ w00, const float* __restrict__ w01,
    const float* __restrict__ w02,
    unsigned short* __restrict__ Mp,
    unsigned short* __restrict__ wA0, unsigned short* __restrict__ wA1)
{
    __shared__ float gram[16][16];
    __shared__ float attn[16][16];
    __shared__ float Msh[16][16];
    const int b = blockIdx.x, t = threadIdx.x;

    if (b == 0) {   // pack conv weights into MFMA A-fragment order
        for (int i = t; i < 512; i += 256) {
            const int c = i >> 6, li = i & 63;
            const int o = li & 15, g = li >> 4;
            int kt = 4 * c + g;
            #pragma unroll
            for (int j = 0; j < 8; ++j) {
                float v = (o < 8 && j < 4) ? w00[(o * 4 + j) * 32 + kt] : 0.f;
                wA0[(c * 64 + li) * 8 + j] = f2bf(v);
            }
            #pragma unroll
            for (int j = 0; j < 8; ++j) {
                float v = 0.f;
                if (o < 8) {
                    if (kt >= 7 && kt <= 22) v = w01[(o * 8 + j) * 16 + (kt - 7)];
                } else {
                    if (!(kt & 1) && kt <= 30) v = w02[((o - 8) * 8 + j) * 16 + (kt >> 1)];
                }
                wA1[(c * 64 + li) * 8 + j] = f2bf(v);
            }
        }
    }

    const float* P = partial + (size_t)b * 2048;
    float s = 0.f;
    #pragma unroll
    for (int k = 0; k < 8; ++k) s += P[k * 256 + t];
    gram[t >> 4][t & 15] = s;
    __syncthreads();
    {
        const float beta = beta_cam[0];
        int d = t & 15;
        float gv = gram[t >> 4][d];
        float rm = gv;
        #pragma unroll
        for (int m = 1; m < 16; m <<= 1) rm = fmaxf(rm, __shfl_xor(rm, m, 64));
        float a = rm - gv;
        float am = a;
        #pragma unroll
        for (int m = 1; m < 16; m <<= 1) am = fmaxf(am, __shfl_xor(am, m, 64));
        float e = __expf(a - am);
        float ssum = e;
        #pragma unroll
        for (int m = 1; m < 16; m <<= 1) ssum += __shfl_xor(ssum, m, 64);
        attn[t >> 4][d] = beta * e / ssum;
    }
    __syncthreads();
    {
        int o = t >> 4, u = t & 15;
        float inv2 = g2[o] * rsqrtf(v2[o] + 1e-5f);
        float sm = wc2[o * 16 + u];
        #pragma unroll
        for (int d = 0; d < 16; ++d) sm += wc2[o * 16 + d] * attn[d][u];
        Msh[o][u] = sm * inv2;
    }
    __syncthreads();
    for (int idx = t; idx < 512; idx += 256) {
        int li = idx >> 3, j = idx & 7;
        int k = 8 * (li >> 4) + j, o = li & 15;
        float v = (k < 16) ? Msh[o][k] : 0.f;
        Mp[(size_t)b * 512 + idx] = f2bf(v);
    }
}

// ---------------------------------------------------------------------------
// kernB: MFMA conv pipeline, constant trip counts, fully unrolled phases.
// grid 256*16, block 256 (4 waves), T=512 positions per block.
// ---------------------------------------------------------------------------
__global__ __launch_bounds__(256, 3) void kernB(
    const float* __restrict__ x,
    const float* __restrict__ b00, const float* __restrict__ b01,
    const float* __restrict__ b02,
    const float* __restrict__ wc1, const float* __restrict__ g1,
    const float* __restrict__ bt1, const float* __restrict__ m1,
    const float* __restrict__ v1,
    const float* __restrict__ g2, const float* __restrict__ bt2,
    const float* __restrict__ m2, const float* __restrict__ v2,
    const unsigned short* __restrict__ wA0, const unsigned short* __restrict__ wA1,
    const unsigned short* __restrict__ Mp, float* __restrict__ out)
{
    __shared__ __align__(16) unsigned short xT[608][8];   // x[p0-32 .. p0+576)
    __shared__ __align__(16) unsigned short f0T[576][8];  // fea0 slot s <-> j = p0-16+s

    const int blk = blockIdx.x;
    const int b  = blk >> 4;
    const int p0 = (blk & 15) << 9;
    const int t  = threadIdx.x;
    const int w  = t >> 6, l = t & 63;
    const int lane15 = l & 15, g = l >> 4;
    const float* xb = x + (size_t)b * 4 * LL;

    // ---- stage xT (bf16, zero outside [0,8192)) ----
    for (int i = t; i < 608; i += 256) {
        int xp = p0 - 32 + i;
        bool ok = (unsigned)xp < 8192u;
        float v0  = ok ? xb[0 * LL + xp] : 0.f;
        float v1_ = ok ? xb[1 * LL + xp] : 0.f;
        float v2_ = ok ? xb[2 * LL + xp] : 0.f;
        float v3_ = ok ? xb[3 * LL + xp] : 0.f;
        uint4 r;
        r.x = cvt_pk_bf16(v0, v1_);
        r.y = cvt_pk_bf16(v2_, v3_);
        r.z = 0u; r.w = 0u;
        *reinterpret_cast<uint4*>(&xT[i][0]) = r;
    }

    // preload phase-1 weights + bias
    bf16x8 a0[8];
    #pragma unroll
    for (int c = 0; c < 8; ++c)
        a0[c] = reinterpret_cast<const bf16x8*>(wA0)[c * 64 + l];
    float b00c[4];
    #pragma unroll
    for (int i = 0; i < 4; ++i) b00c[i] = b00[(4 * g + i) & 7];

    __syncthreads();

    // ---- phase 1: fea0 via MFMA, 9 iterations per wave, fully unrolled ----
    {
        const int gj0 = 9 * w;
        const int rb = lane15 + g;
        bf16x8 bb[8];
        {
            int base = 16 * gj0 + rb;
            #pragma unroll
            for (int c = 0; c < 8; ++c)
                bb[c] = *reinterpret_cast<const bf16x8*>(&xT[base + 4 * c][0]);
        }
        #pragma unroll
        for (int it = 0; it < 9; ++it) {
            f32x4 d = {0.f, 0.f, 0.f, 0.f};
            #pragma unroll
            for (int c = 0; c < 8; ++c)
                d = __builtin_amdgcn_mfma_f32_16x16x32_bf16(a0[c], bb[c], d, 0, 0, 0);
            if (g < 2) {
                int s = 16 * (gj0 + it) + lane15;
                int j = p0 - 16 + s;
                bool ok = (unsigned)j <= 8192u;
                float e0 = ok ? d[0] + b00c[0] : 0.f;
                float e1 = ok ? d[1] + b00c[1] : 0.f;
                float e2 = ok ? d[2] + b00c[2] : 0.f;
                float e3 = ok ? d[3] + b00c[3] : 0.f;
                uint2 wv;
                wv.x = cvt_pk_bf16(e0, e1);
                wv.y = cvt_pk_bf16(e2, e3);
                *reinterpret_cast<uint2*>(&f0T[s][4 * g]) = wv;
            }
            if (it < 8) {
                #pragma unroll
                for (int c = 0; c < 4; ++c) bb[c] = bb[c + 4];
                int base = 16 * (gj0 + it + 1) + rb;
                #pragma unroll
                for (int c = 4; c < 8; ++c)
                    bb[c] = *reinterpret_cast<const bf16x8*>(&xT[base + 4 * c][0]);
            }
        }
    }

    // preload phase-2 constants
    bf16x8 a1[8];
    #pragma unroll
    for (int c = 0; c < 8; ++c)
        a1[c] = reinterpret_cast<const bf16x8*>(wA1)[c * 64 + l];
    bf16x8 mfrag = reinterpret_cast<const bf16x8*>(Mp)[b * 64 + l];
    float wfv[8][4], bf1v[8];
    #pragma unroll
    for (int j = 0; j < 8; ++j) {
        int u = (8 * g + j) & 15;
        float inv = g1[u] * rsqrtf(v1[u] + 1e-5f);
        #pragma unroll
        for (int c = 0; c < 4; ++c) wfv[j][c] = wc1[u * 4 + c] * inv;
        bf1v[j] = bt1[u] - m1[u] * inv;
    }
    float cb1[4], bf2v[4];
    #pragma unroll
    for (int i = 0; i < 4; ++i) {
        int o = 4 * g + i;
        cb1[i] = (o < 8) ? b01[o] : b02[o - 8];
        float inv2 = g2[o] * rsqrtf(v2[o] + 1e-5f);
        bf2v[i] = bt2[o] - m2[o] * inv2;
    }

    __syncthreads();

    // ---- phase 2: fusion + c2 + store, 8 iterations, fully unrolled ----
    {
        const int gi0 = 8 * w;
        const int rb = lane15 + g + 2;
        bf16x8 bb[8];
        {
            int base = 16 * gi0 + rb;
            #pragma unroll
            for (int c = 0; c < 8; ++c)
                bb[c] = *reinterpret_cast<const bf16x8*>(&f0T[base + 4 * c][0]);
        }
        float* ob = out + (size_t)b * 16 * LL;
        #pragma unroll
        for (int it = 0; it < 8; ++it) {
            f32x4 dF = {0.f, 0.f, 0.f, 0.f};
            #pragma unroll
            for (int c = 0; c < 8; ++c)
                dF = __builtin_amdgcn_mfma_f32_16x16x32_bf16(a1[c], bb[c], dF, 0, 0, 0);
            // c0 B-fragment (lanes g<2 own u = 8g+j)
            U4 uu; uu.u.x = 0u; uu.u.y = 0u; uu.u.z = 0u; uu.u.w = 0u;
            if (g < 2) {
                const uint2 xr = *reinterpret_cast<const uint2*>(
                    &xT[32 + 16 * (gi0 + it) + lane15][0]);
                float xc0 = bf2f_lo(xr.x), xc1 = bf2f_hi(xr.x);
                float xc2 = bf2f_lo(xr.y), xc3 = bf2f_hi(xr.y);
                float cu[8];
                #pragma unroll
                for (int j = 0; j < 8; ++j)
                    cu[j] = fmaxf(bf1v[j] + wfv[j][0] * xc0 + wfv[j][1] * xc1
                                 + wfv[j][2] * xc2 + wfv[j][3] * xc3, 0.f);
                uu.u.x = cvt_pk_bf16(cu[0], cu[1]);
                uu.u.y = cvt_pk_bf16(cu[2], cu[3]);
                uu.u.z = cvt_pk_bf16(cu[4], cu[5]);
                uu.u.w = cvt_pk_bf16(cu[6], cu[7]);
            }
            f32x4 zc = {0.f, 0.f, 0.f, 0.f};
            f32x4 dC = __builtin_amdgcn_mfma_f32_16x16x32_bf16(mfrag, uu.v, zc, 0, 0, 0);

            const int p = p0 + 16 * (gi0 + it) + lane15;
            const bool edge = (p < 1) | (p > LL - 3);
            float* op = ob + p;
            #pragma unroll
            for (int i = 0; i < 4; ++i) {
                int o = 4 * g + i;
                float vf = dF[i] + cb1[i];
                if (o >= 8 && edge) vf = 0.f;
                float c2 = fmaxf(dC[i] + bf2v[i], 0.f);
                op[(size_t)o * LL] = vf + c2;
            }
            if (it < 7) {
                #pragma unroll
                for (int c = 0; c < 4; ++c) bb[c] = bb[c + 4];
                int base = 16 * (gi0 + it + 1) + rb;
                #pragma unroll
                for (int c = 4; c < 8; ++c)
                    bb[c] = *reinterpret_cast<const bf16x8*>(&f0T[base + 4 * c][0]);
            }
        }
    }
}

extern "C" void kernel_launch(void* const* d_in, const int* in_sizes, int n_in,
                              void* d_out, int out_size, void* d_ws, size_t ws_size,
                              hipStream_t stream)
{
    const float* x    = (const float*)d_in[0];
    const float* w00  = (const float*)d_in[1];
    const float* b00  = (const float*)d_in[2];
    const float* w01  = (const float*)d_in[3];
    const float* b01  = (const float*)d_in[4];
    const float* w02  = (const float*)d_in[5];
    const float* b02  = (const float*)d_in[6];
    const float* wc1  = (const float*)d_in[7];
    const float* g1   = (const float*)d_in[8];
    const float* bt1  = (const float*)d_in[9];
    const float* m1   = (const float*)d_in[10];
    const float* v1   = (const float*)d_in[11];
    const float* beta = (const float*)d_in[12];
    const float* wc2  = (const float*)d_in[13];
    const float* g2   = (const float*)d_in[14];
    const float* bt2  = (const float*)d_in[15];
    const float* m2   = (const float*)d_in[16];
    const float* v2   = (const float*)d_in[17];

    char* wsb = (char*)d_ws;
    float* partialp      = (float*)wsb;                       // 2048*256*4 = 2,097,152 B
    unsigned short* Mpp  = (unsigned short*)(wsb + 2097152);  // 262,144 B
    unsigned short* wA0p = (unsigned short*)(wsb + 2359296);  // 8,192 B
    unsigned short* wA1p = (unsigned short*)(wsb + 2367488);  // 8,192 B
    float* o = (float*)d_out;

    hipLaunchKernelGGL(kernA1, dim3(2048), dim3(256), 0, stream,
        x, wc1, g1, bt1, m1, v1, partialp);
    hipLaunchKernelGGL(kernA2, dim3(256), dim3(256), 0, stream,
        partialp, beta, wc2, g2, bt2, m2, v2, w00, w01, w02, Mpp, wA0p, wA1p);
    hipLaunchKernelGGL(kernB, dim3(4096), dim3(256), 0, stream,
        x, b00, b01, b02, wc1, g1, bt1, m1, v1, g2, bt2, m2, v2,
        wA0p, wA1p, Mpp, o);
}

// Round 5
// 89.293 us; speedup vs baseline: 11.6259x; 1.0717x over previous
//
#include <hip/hip_runtime.h>

#define LL 8192

typedef __attribute__((ext_vector_type(8))) short bf16x8;
typedef __attribute__((ext_vector_type(4))) float f32x4;

union U4 { uint4 u; bf16x8 v; };

__device__ __forceinline__ unsigned short f2bf(float f) {
    union { float f; unsigned u; } v; v.f = f;
    unsigned r = v.u + 0x7fffu + ((v.u >> 16) & 1u);
    return (unsigned short)(r >> 16);
}
__device__ __forceinline__ unsigned cvt_pk_bf16(float lo, float hi) {
    unsigned r;
    asm("v_cvt_pk_bf16_f32 %0, %1, %2" : "=v"(r) : "v"(lo), "v"(hi));
    return r;
}
__device__ __forceinline__ float bf2f_lo(unsigned u) {
    union { unsigned u; float f; } v; v.u = u << 16; return v.f;
}
__device__ __forceinline__ float bf2f_hi(unsigned u) {
    union { unsigned u; float f; } v; v.u = u & 0xffff0000u; return v.f;
}

// ---------------------------------------------------------------------------
// kernA1: Gram of c0 over a 1024-position chunk via MFMA (A-frag == B-frag).
// grid = 256*8, block = 256
// ---------------------------------------------------------------------------
__global__ __launch_bounds__(256) void kernA1(
    const float* __restrict__ x, const float* __restrict__ wc1,
    const float* __restrict__ g1, const float* __restrict__ bt1,
    const float* __restrict__ m1, const float* __restrict__ v1,
    float* __restrict__ partial)
{
    __shared__ float xs[4][1024];                         // 16 KB (reused for gsum)
    __shared__ __align__(16) unsigned short c0f[16384];   // 32 KB frag-slot layout
    __shared__ float wf1[16][4];
    __shared__ float bf1[16];

    const int blk = blockIdx.x;
    const int b = blk >> 3, chunk = blk & 7;
    const int t = threadIdx.x;
    const int w = t >> 6, l = t & 63;
    const float* xb = x + (size_t)b * 4 * LL;
    const int p0 = chunk << 10;

    if (t < 16) {
        float inv = g1[t] * rsqrtf(v1[t] + 1e-5f);
        #pragma unroll
        for (int c = 0; c < 4; ++c) wf1[t][c] = wc1[t * 4 + c] * inv;
        bf1[t] = bt1[t] - m1[t] * inv;
    }
    #pragma unroll
    for (int c = 0; c < 4; ++c)
        for (int j = t; j < 1024; j += 256)
            xs[c][j] = xb[c * LL + p0 + j];
    __syncthreads();

    {
        const int u = t & 15, pblk = t >> 4;
        float w0 = wf1[u][0], w1 = wf1[u][1], w2 = wf1[u][2], w3 = wf1[u][3];
        float bu = bf1[u];
        #pragma unroll 4
        for (int pp = 0; pp < 64; pp += 2) {
            int p = (pblk << 6) + pp;
            float c00 = fmaxf(bu + w0 * xs[0][p] + w1 * xs[1][p]
                                 + w2 * xs[2][p] + w3 * xs[3][p], 0.f);
            float c01 = fmaxf(bu + w0 * xs[0][p + 1] + w1 * xs[1][p + 1]
                                 + w2 * xs[2][p + 1] + w3 * xs[3][p + 1], 0.f);
            int slot = ((p >> 5) << 6) + (((p >> 3) & 3) << 4) + u;
            *reinterpret_cast<unsigned*>(&c0f[slot * 8 + (p & 7)]) =
                cvt_pk_bf16(c00, c01);
        }
    }
    __syncthreads();

    f32x4 acc = {0.f, 0.f, 0.f, 0.f};
    #pragma unroll
    for (int m = 0; m < 8; ++m) {
        int slot = (w * 8 + m) * 64 + l;
        bf16x8 fr = *reinterpret_cast<const bf16x8*>(&c0f[slot * 8]);
        acc = __builtin_amdgcn_mfma_f32_16x16x32_bf16(fr, fr, acc, 0, 0, 0);
    }

    float* gsumf = &xs[0][0];
    {
        int col = l & 15, rg = l >> 4;
        #pragma unroll
        for (int i = 0; i < 4; ++i)
            gsumf[w * 256 + (rg * 4 + i) * 16 + col] = acc[i];
    }
    __syncthreads();
    partial[(size_t)(b * 8 + chunk) * 256 + t] =
        gsumf[t] + gsumf[256 + t] + gsumf[512 + t] + gsumf[768 + t];
}

// ---------------------------------------------------------------------------
// kernA2: reduce partials -> softmax -> M -> Mp; block 0 also packs weights.
// grid 256
// ---------------------------------------------------------------------------
__global__ __launch_bounds__(256) void kernA2(
    const float* __restrict__ partial, const float* __restrict__ beta_cam,
    const float* __restrict__ wc2, const float* __restrict__ g2,
    const float* __restrict__ bt2, const float* __restrict__ m2,
    const float* __restrict__ v2,
    const float* __restrict__ w00, const float* __restrict__ w01,
    const float* __restrict__ w02,
    unsigned short* __restrict__ Mp,
    unsigned short* __restrict__ wA0, unsigned short* __restrict__ wA1)
{
    __shared__ float gram[16][16];
    __shared__ float attn[16][16];
    __shared__ float Msh[16][16];
    const int b = blockIdx.x, t = threadIdx.x;

    if (b == 0) {   // pack conv weights into MFMA A-fragment order (6 chunks each)
        for (int i = t; i < 384; i += 256) {
            const int c = i >> 6, li = i & 63;
            const int row = li & 15, g = li >> 4;
            // ---- wA0: fea0 dual-position packing ----
            // k=8g+j: tap T = 8c+g+4*(j>=4), ch = j&3.
            // rows 0..7: w00[row][ch][T] (T<32); rows 8..15: w00[row-8][ch][T-16] (T>=16)
            #pragma unroll
            for (int j = 0; j < 8; ++j) {
                int ch = j & 3;
                int T = 8 * c + g + ((j >= 4) ? 4 : 0);
                float v = 0.f;
                if (row < 8) {
                    if (T < 32) v = w00[(row * 4 + ch) * 32 + T];
                } else {
                    int tt = T - 16;
                    if (tt >= 0) v = w00[((row - 8) * 4 + ch) * 32 + tt];
                }
                wA0[(c * 64 + li) * 8 + j] = f2bf(v);
            }
            // ---- wA1: fusion sparse-q packing ----
            // qtab: c=0 -> 2g; c=1..4 -> 3+4c+g; c=5 -> 24+2g
            int q = (c == 0) ? 2 * g : (c == 5) ? 24 + 2 * g : 3 + 4 * c + g;
            #pragma unroll
            for (int j = 0; j < 8; ++j) {
                float v = 0.f;
                if (row < 8) {
                    if (q >= 7 && q <= 22) v = w01[(row * 8 + j) * 16 + (q - 7)];
                } else {
                    if (!(q & 1)) v = w02[((row - 8) * 8 + j) * 16 + (q >> 1)];
                }
                wA1[(c * 64 + li) * 8 + j] = f2bf(v);
            }
        }
    }

    const float* P = partial + (size_t)b * 2048;
    float s = 0.f;
    #pragma unroll
    for (int k = 0; k < 8; ++k) s += P[k * 256 + t];
    gram[t >> 4][t & 15] = s;
    __syncthreads();
    {
        const float beta = beta_cam[0];
        int d = t & 15;
        float gv = gram[t >> 4][d];
        float rm = gv;
        #pragma unroll
        for (int m = 1; m < 16; m <<= 1) rm = fmaxf(rm, __shfl_xor(rm, m, 64));
        float a = rm - gv;
        float am = a;
        #pragma unroll
        for (int m = 1; m < 16; m <<= 1) am = fmaxf(am, __shfl_xor(am, m, 64));
        float e = __expf(a - am);
        float ssum = e;
        #pragma unroll
        for (int m = 1; m < 16; m <<= 1) ssum += __shfl_xor(ssum, m, 64);
        attn[t >> 4][d] = beta * e / ssum;
    }
    __syncthreads();
    {
        int o = t >> 4, u = t & 15;
        float inv2 = g2[o] * rsqrtf(v2[o] + 1e-5f);
        float sm = wc2[o * 16 + u];
        #pragma unroll
        for (int d = 0; d < 16; ++d) sm += wc2[o * 16 + d] * attn[d][u];
        Msh[o][u] = sm * inv2;
    }
    __syncthreads();
    for (int idx = t; idx < 512; idx += 256) {
        int li = idx >> 3, j = idx & 7;
        int k = 8 * (li >> 4) + j, o = li & 15;
        float v = (k < 16) ? Msh[o][k] : 0.f;
        Mp[(size_t)b * 512 + idx] = f2bf(v);
    }
}

// ---------------------------------------------------------------------------
// kernB: MFMA conv pipeline with dual-packed K (phase 1) and sparse-q (phase 2).
// grid 256*16, block 256 (4 waves), T=512 positions per block.
// ---------------------------------------------------------------------------
__global__ __launch_bounds__(256, 3) void kernB(
    const float* __restrict__ x,
    const float* __restrict__ b00, const float* __restrict__ b01,
    const float* __restrict__ b02,
    const float* __restrict__ wc1, const float* __restrict__ g1,
    const float* __restrict__ bt1, const float* __restrict__ m1,
    const float* __restrict__ v1,
    const float* __restrict__ g2, const float* __restrict__ bt2,
    const float* __restrict__ m2, const float* __restrict__ v2,
    const unsigned short* __restrict__ wA0, const unsigned short* __restrict__ wA1,
    const unsigned short* __restrict__ Mp, float* __restrict__ out)
{
    // xT row i: elems 0..3 = x[0..3][p0-32+i], elems 4..7 = x[0..3][p0-32+i+4]
    __shared__ __align__(16) unsigned short xT[608][8];
    __shared__ __align__(16) unsigned short f0T[576][8];  // slot s <-> j = p0-16+s

    const int blk = blockIdx.x;
    const int b  = blk >> 4;
    const int p0 = (blk & 15) << 9;
    const int t  = threadIdx.x;
    const int w  = t >> 6, l = t & 63;
    const int lane15 = l & 15, g = l >> 4;
    const float* xb = x + (size_t)b * 4 * LL;

    // ---- stage xT: one load per row, written to row i lower + row i-4 upper ----
    for (int i = t; i < 608; i += 256) {
        int xp = p0 - 32 + i;
        bool ok = (unsigned)xp < 8192u;
        float v0  = ok ? xb[0 * LL + xp] : 0.f;
        float v1_ = ok ? xb[1 * LL + xp] : 0.f;
        float v2_ = ok ? xb[2 * LL + xp] : 0.f;
        float v3_ = ok ? xb[3 * LL + xp] : 0.f;
        uint2 r;
        r.x = cvt_pk_bf16(v0, v1_);
        r.y = cvt_pk_bf16(v2_, v3_);
        *reinterpret_cast<uint2*>(&xT[i][0]) = r;          // lower half of row i
        if (i >= 4)
            *reinterpret_cast<uint2*>(&xT[i - 4][4]) = r;  // upper half of row i-4
    }

    // preload phase-1 weights + bias
    bf16x8 a0[6];
    #pragma unroll
    for (int c = 0; c < 6; ++c)
        a0[c] = reinterpret_cast<const bf16x8*>(wA0)[c * 64 + l];
    float b00c[4];
    #pragma unroll
    for (int i = 0; i < 4; ++i) b00c[i] = b00[(4 * g + i) & 7];

    __syncthreads();

    // ---- phase 1: fea0 via dual-packed MFMA, 32 positions per 6-MFMA group ----
    {
        const int ngrp = (w < 2) ? 5 : 4;
        const int grp0 = (w < 2) ? 5 * w : 10 + 4 * (w - 2);
        const int rb = 32 * grp0 + lane15 + g;
        bf16x8 bb[6];
        #pragma unroll
        for (int c = 0; c < 6; ++c)
            bb[c] = *reinterpret_cast<const bf16x8*>(&xT[rb + 8 * c][0]);
        #pragma unroll
        for (int it = 0; it < 5; ++it) {
            if (it < ngrp) {
                f32x4 d = {0.f, 0.f, 0.f, 0.f};
                #pragma unroll
                for (int c = 0; c < 6; ++c)
                    d = __builtin_amdgcn_mfma_f32_16x16x32_bf16(a0[c], bb[c], d, 0, 0, 0);
                int s = 32 * (grp0 + it) + lane15 + ((g >= 2) ? 16 : 0);
                int j = p0 - 16 + s;
                bool ok = (unsigned)j <= 8192u;
                float e0 = ok ? d[0] + b00c[0] : 0.f;
                float e1 = ok ? d[1] + b00c[1] : 0.f;
                float e2 = ok ? d[2] + b00c[2] : 0.f;
                float e3 = ok ? d[3] + b00c[3] : 0.f;
                uint2 wv;
                wv.x = cvt_pk_bf16(e0, e1);
                wv.y = cvt_pk_bf16(e2, e3);
                *reinterpret_cast<uint2*>(&f0T[s][4 * (g & 1)]) = wv;
                if (it + 1 < ngrp) {       // slide window: chunks 4,5 -> 0,1
                    bb[0] = bb[4]; bb[1] = bb[5];
                    int nb = rb + 32 * (it + 1);
                    #pragma unroll
                    for (int c = 2; c < 6; ++c)
                        bb[c] = *reinterpret_cast<const bf16x8*>(&xT[nb + 8 * c][0]);
                }
            }
        }
    }

    // preload phase-2 constants
    bf16x8 a1[6];
    #pragma unroll
    for (int c = 0; c < 6; ++c)
        a1[c] = reinterpret_cast<const bf16x8*>(wA1)[c * 64 + l];
    bf16x8 mfrag = reinterpret_cast<const bf16x8*>(Mp)[b * 64 + l];
    float wfv[8][4], bf1v[8];
    #pragma unroll
    for (int j = 0; j < 8; ++j) {
        int u = (8 * g + j) & 15;
        float inv = g1[u] * rsqrtf(v1[u] + 1e-5f);
        #pragma unroll
        for (int c = 0; c < 4; ++c) wfv[j][c] = wc1[u * 4 + c] * inv;
        bf1v[j] = bt1[u] - m1[u] * inv;
    }
    float cb1[4], bf2v[4];
    #pragma unroll
    for (int i = 0; i < 4; ++i) {
        int o = 4 * g + i;
        cb1[i] = (o < 8) ? b01[o] : b02[o - 8];
        float inv2 = g2[o] * rsqrtf(v2[o] + 1e-5f);
        bf2v[i] = bt2[o] - m2[o] * inv2;
    }
    // per-lane sparse-q read offsets (q + 2 baked in)
    int qoff[6];
    qoff[0] = 2 * g + 2;  qoff[1] = 9 + g;   qoff[2] = 13 + g;
    qoff[3] = 17 + g;     qoff[4] = 21 + g;  qoff[5] = 26 + 2 * g;

    __syncthreads();

    // ---- phase 2: fusion (6 sparse chunks) + c2 + store ----
    {
        float* ob = out + (size_t)b * 16 * LL;
        #pragma unroll
        for (int it = 0; it < 8; ++it) {
            const int gi = 8 * w + it;
            const int rbase = 16 * gi + lane15;
            bf16x8 bb[6];
            #pragma unroll
            for (int c = 0; c < 6; ++c)
                bb[c] = *reinterpret_cast<const bf16x8*>(&f0T[rbase + qoff[c]][0]);
            f32x4 dF = {0.f, 0.f, 0.f, 0.f};
            #pragma unroll
            for (int c = 0; c < 6; ++c)
                dF = __builtin_amdgcn_mfma_f32_16x16x32_bf16(a1[c], bb[c], dF, 0, 0, 0);
            // c0 B-fragment (lanes g<2 own u = 8g+j)
            U4 uu; uu.u.x = 0u; uu.u.y = 0u; uu.u.z = 0u; uu.u.w = 0u;
            if (g < 2) {
                const uint2 xr = *reinterpret_cast<const uint2*>(&xT[rbase + 32][0]);
                float xc0 = bf2f_lo(xr.x), xc1 = bf2f_hi(xr.x);
                float xc2 = bf2f_lo(xr.y), xc3 = bf2f_hi(xr.y);
                float cu[8];
                #pragma unroll
                for (int j = 0; j < 8; ++j)
                    cu[j] = fmaxf(bf1v[j] + wfv[j][0] * xc0 + wfv[j][1] * xc1
                                 + wfv[j][2] * xc2 + wfv[j][3] * xc3, 0.f);
                uu.u.x = cvt_pk_bf16(cu[0], cu[1]);
                uu.u.y = cvt_pk_bf16(cu[2], cu[3]);
                uu.u.z = cvt_pk_bf16(cu[4], cu[5]);
                uu.u.w = cvt_pk_bf16(cu[6], cu[7]);
            }
            f32x4 zc = {0.f, 0.f, 0.f, 0.f};
            f32x4 dC = __builtin_amdgcn_mfma_f32_16x16x32_bf16(mfrag, uu.v, zc, 0, 0, 0);

            const int p = p0 + 16 * gi + lane15;
            const bool edge = (p < 1) | (p > LL - 3);
            float* op = ob + p;
            #pragma unroll
            for (int i = 0; i < 4; ++i) {
                int o = 4 * g + i;
                float vf = dF[i] + cb1[i];
                if (o >= 8 && edge) vf = 0.f;
                float c2 = fmaxf(dC[i] + bf2v[i], 0.f);
                op[(size_t)o * LL] = vf + c2;
            }
        }
    }
}

extern "C" void kernel_launch(void* const* d_in, const int* in_sizes, int n_in,
                              void* d_out, int out_size, void* d_ws, size_t ws_size,
                              hipStream_t stream)
{
    const float* x    = (const float*)d_in[0];
    const float* w00  = (const float*)d_in[1];
    const float* b00  = (const float*)d_in[2];
    const float* w01  = (const float*)d_in[3];
    const float* b01  = (const float*)d_in[4];
    const float* w02  = (const float*)d_in[5];
    const float* b02  = (const float*)d_in[6];
    const float* wc1  = (const float*)d_in[7];
    const float* g1   = (const float*)d_in[8];
    const float* bt1  = (const float*)d_in[9];
    const float* m1   = (const float*)d_in[10];
    const float* v1   = (const float*)d_in[11];
    const float* beta = (const float*)d_in[12];
    const float* wc2  = (const float*)d_in[13];
    const float* g2   = (const float*)d_in[14];
    const float* bt2  = (const float*)d_in[15];
    const float* m2   = (const float*)d_in[16];
    const float* v2   = (const float*)d_in[17];

    char* wsb = (char*)d_ws;
    float* partialp      = (float*)wsb;                       // 2,097,152 B
    unsigned short* Mpp  = (unsigned short*)(wsb + 2097152);  // 262,144 B
    unsigned short* wA0p = (unsigned short*)(wsb + 2359296);  // 6,144 B
    unsigned short* wA1p = (unsigned short*)(wsb + 2365440);  // 6,144 B
    float* o = (float*)d_out;

    hipLaunchKernelGGL(kernA1, dim3(2048), dim3(256), 0, stream,
        x, wc1, g1, bt1, m1, v1, partialp);
    hipLaunchKernelGGL(kernA2, dim3(256), dim3(256), 0, stream,
        partialp, beta, wc2, g2, bt2, m2, v2, w00, w01, w02, Mpp, wA0p, wA1p);
    hipLaunchKernelGGL(kernB, dim3(4096), dim3(256), 0, stream,
        x, b00, b01, b02, wc1, g1, bt1, m1, v1, g2, bt2, m2, v2,
        wA0p, wA1p, Mpp, o);
}

// Round 6
// 81.126 us; speedup vs baseline: 12.7962x; 1.1007x over previous
//
#include <hip/hip_runtime.h>

#define LL 8192

typedef __attribute__((ext_vector_type(8))) short bf16x8;
typedef __attribute__((ext_vector_type(4))) float f32x4;

union U4 { uint4 u; bf16x8 v; };

__device__ __forceinline__ unsigned short f2bf(float f) {
    union { float f; unsigned u; } v; v.f = f;
    unsigned r = v.u + 0x7fffu + ((v.u >> 16) & 1u);
    return (unsigned short)(r >> 16);
}
__device__ __forceinline__ unsigned cvt_pk_bf16(float lo, float hi) {
    unsigned r;
    asm("v_cvt_pk_bf16_f32 %0, %1, %2" : "=v"(r) : "v"(lo), "v"(hi));
    return r;
}

// ---------------------------------------------------------------------------
// kernA1: Gram of c0 over a 1024-position chunk via MFMA (A-frag == B-frag).
// grid = 256*8, block = 256
// ---------------------------------------------------------------------------
__global__ __launch_bounds__(256) void kernA1(
    const float* __restrict__ x, const float* __restrict__ wc1,
    const float* __restrict__ g1, const float* __restrict__ bt1,
    const float* __restrict__ m1, const float* __restrict__ v1,
    float* __restrict__ partial)
{
    __shared__ float xs[4][1024];                         // 16 KB (reused for gsum)
    __shared__ __align__(16) unsigned short c0f[16384];   // 32 KB frag-slot layout
    __shared__ float wf1[16][4];
    __shared__ float bf1[16];

    const int blk = blockIdx.x;
    const int b = blk >> 3, chunk = blk & 7;
    const int t = threadIdx.x;
    const int w = t >> 6, l = t & 63;
    const float* xb = x + (size_t)b * 4 * LL;
    const int p0 = chunk << 10;

    if (t < 16) {
        float inv = g1[t] * rsqrtf(v1[t] + 1e-5f);
        #pragma unroll
        for (int c = 0; c < 4; ++c) wf1[t][c] = wc1[t * 4 + c] * inv;
        bf1[t] = bt1[t] - m1[t] * inv;
    }
    #pragma unroll
    for (int c = 0; c < 4; ++c)
        for (int j = t; j < 1024; j += 256)
            xs[c][j] = xb[c * LL + p0 + j];
    __syncthreads();

    {
        const int u = t & 15, pblk = t >> 4;
        float w0 = wf1[u][0], w1 = wf1[u][1], w2 = wf1[u][2], w3 = wf1[u][3];
        float bu = bf1[u];
        #pragma unroll 4
        for (int pp = 0; pp < 64; pp += 2) {
            int p = (pblk << 6) + pp;
            float c00 = fmaxf(bu + w0 * xs[0][p] + w1 * xs[1][p]
                                 + w2 * xs[2][p] + w3 * xs[3][p], 0.f);
            float c01 = fmaxf(bu + w0 * xs[0][p + 1] + w1 * xs[1][p + 1]
                                 + w2 * xs[2][p + 1] + w3 * xs[3][p + 1], 0.f);
            int slot = ((p >> 5) << 6) + (((p >> 3) & 3) << 4) + u;
            *reinterpret_cast<unsigned*>(&c0f[slot * 8 + (p & 7)]) =
                cvt_pk_bf16(c00, c01);
        }
    }
    __syncthreads();

    f32x4 acc = {0.f, 0.f, 0.f, 0.f};
    #pragma unroll
    for (int m = 0; m < 8; ++m) {
        int slot = (w * 8 + m) * 64 + l;
        bf16x8 fr = *reinterpret_cast<const bf16x8*>(&c0f[slot * 8]);
        acc = __builtin_amdgcn_mfma_f32_16x16x32_bf16(fr, fr, acc, 0, 0, 0);
    }

    float* gsumf = &xs[0][0];
    {
        int col = l & 15, rg = l >> 4;
        #pragma unroll
        for (int i = 0; i < 4; ++i)
            gsumf[w * 256 + (rg * 4 + i) * 16 + col] = acc[i];
    }
    __syncthreads();
    partial[(size_t)(b * 8 + chunk) * 256 + t] =
        gsumf[t] + gsumf[256 + t] + gsumf[512 + t] + gsumf[768 + t];
}

// ---------------------------------------------------------------------------
// kernA2: reduce partials -> softmax -> M -> Mp; block 0 also packs weights.
// grid 256
// ---------------------------------------------------------------------------
__global__ __launch_bounds__(256) void kernA2(
    const float* __restrict__ partial, const float* __restrict__ beta_cam,
    const float* __restrict__ wc2, const float* __restrict__ g2,
    const float* __restrict__ bt2, const float* __restrict__ m2,
    const float* __restrict__ v2,
    const float* __restrict__ w00, const float* __restrict__ w01,
    const float* __restrict__ w02,
    const float* __restrict__ wc1, const float* __restrict__ g1,
    const float* __restrict__ bt1, const float* __restrict__ m1,
    const float* __restrict__ v1,
    unsigned short* __restrict__ Mp,
    unsigned short* __restrict__ wA0, unsigned short* __restrict__ wA1,
    unsigned short* __restrict__ wc0A)
{
    __shared__ float gram[16][16];
    __shared__ float attn[16][16];
    __shared__ float Msh[16][16];
    const int b = blockIdx.x, t = threadIdx.x;

    if (b == 0) {   // pack conv weights into MFMA A-fragment order
        for (int i = t; i < 384; i += 256) {
            const int c = i >> 6, li = i & 63;
            const int row = li & 15, g = li >> 4;
            // ---- wA0: fea0 dual-position packing ----
            #pragma unroll
            for (int j = 0; j < 8; ++j) {
                int ch = j & 3;
                int T = 8 * c + g + ((j >= 4) ? 4 : 0);
                float v = 0.f;
                if (row < 8) {
                    if (T < 32) v = w00[(row * 4 + ch) * 32 + T];
                } else {
                    int tt = T - 16;
                    if (tt >= 0) v = w00[((row - 8) * 4 + ch) * 32 + tt];
                }
                wA0[(c * 64 + li) * 8 + j] = f2bf(v);
            }
            // ---- wA1: fusion sparse-q packing ----
            int q = (c == 0) ? 2 * g : (c == 5) ? 24 + 2 * g : 3 + 4 * c + g;
            #pragma unroll
            for (int j = 0; j < 8; ++j) {
                float v = 0.f;
                if (row < 8) {
                    if (q >= 7 && q <= 22) v = w01[(row * 8 + j) * 16 + (q - 7)];
                } else {
                    if (!(q & 1)) v = w02[((row - 8) * 8 + j) * 16 + (q >> 1)];
                }
                wA1[(c * 64 + li) * 8 + j] = f2bf(v);
            }
        }
        // ---- wc0A: c0 1x1-conv A-frag, bias folded at k=4 ----
        if (t < 64) {
            int u = t & 15, gg = t >> 4;
            float inv = g1[u] * rsqrtf(v1[u] + 1e-5f);
            #pragma unroll
            for (int j = 0; j < 8; ++j) {
                float v = 0.f;
                if (gg == 0) {
                    if (j < 4) v = wc1[u * 4 + j] * inv;
                    else if (j == 4) v = bt1[u] - m1[u] * inv;
                }
                wc0A[t * 8 + j] = f2bf(v);
            }
        }
    }

    const float* P = partial + (size_t)b * 2048;
    float s = 0.f;
    #pragma unroll
    for (int k = 0; k < 8; ++k) s += P[k * 256 + t];
    gram[t >> 4][t & 15] = s;
    __syncthreads();
    {
        const float beta = beta_cam[0];
        int d = t & 15;
        float gv = gram[t >> 4][d];
        float rm = gv;
        #pragma unroll
        for (int m = 1; m < 16; m <<= 1) rm = fmaxf(rm, __shfl_xor(rm, m, 64));
        float a = rm - gv;
        float am = a;
        #pragma unroll
        for (int m = 1; m < 16; m <<= 1) am = fmaxf(am, __shfl_xor(am, m, 64));
        float e = __expf(a - am);
        float ssum = e;
        #pragma unroll
        for (int m = 1; m < 16; m <<= 1) ssum += __shfl_xor(ssum, m, 64);
        attn[t >> 4][d] = beta * e / ssum;
    }
    __syncthreads();
    {
        int o = t >> 4, u = t & 15;
        float inv2 = g2[o] * rsqrtf(v2[o] + 1e-5f);
        float sm = wc2[o * 16 + u];
        #pragma unroll
        for (int d = 0; d < 16; ++d) sm += wc2[o * 16 + d] * attn[d][u];
        Msh[o][u] = sm * inv2;
    }
    __syncthreads();
    for (int idx = t; idx < 512; idx += 256) {
        int li = idx >> 3, j = idx & 7;
        int k = 8 * (li >> 4) + j, o = li & 15;
        float v = (k < 16) ? Msh[o][k] : 0.f;
        Mp[(size_t)b * 512 + idx] = f2bf(v);
    }
}

// ---------------------------------------------------------------------------
// kernB: MFMA conv pipeline; c0 and c2 fully on MFMA (no scalar matvec).
// grid 256*16, block 256 (4 waves), T=512 positions per block.
// ---------------------------------------------------------------------------
__global__ __launch_bounds__(256, 4) void kernB(
    const float* __restrict__ x,
    const float* __restrict__ b00, const float* __restrict__ b01,
    const float* __restrict__ b02,
    const float* __restrict__ g2, const float* __restrict__ bt2,
    const float* __restrict__ m2, const float* __restrict__ v2,
    const unsigned short* __restrict__ wA0, const unsigned short* __restrict__ wA1,
    const unsigned short* __restrict__ wc0A,
    const unsigned short* __restrict__ Mp, float* __restrict__ out)
{
    // xT row i: elems 0..3 = x[0..3][p0-32+i], elems 4..7 = x[0..3][p0-32+i+4]
    __shared__ __align__(16) unsigned short xT[608][8];
    __shared__ __align__(16) unsigned short f0T[576][8];  // slot s <-> j = p0-16+s

    const int blk = blockIdx.x;
    const int b  = blk >> 4;
    const int p0 = (blk & 15) << 9;
    const int t  = threadIdx.x;
    const int w  = t >> 6, l = t & 63;
    const int lane15 = l & 15, g = l >> 4;
    const float* xb = x + (size_t)b * 4 * LL;

    // ---- stage xT: one load per row, written to row i lower + row i-4 upper ----
    for (int i = t; i < 608; i += 256) {
        int xp = p0 - 32 + i;
        bool ok = (unsigned)xp < 8192u;
        float v0  = ok ? xb[0 * LL + xp] : 0.f;
        float v1_ = ok ? xb[1 * LL + xp] : 0.f;
        float v2_ = ok ? xb[2 * LL + xp] : 0.f;
        float v3_ = ok ? xb[3 * LL + xp] : 0.f;
        uint2 r;
        r.x = cvt_pk_bf16(v0, v1_);
        r.y = cvt_pk_bf16(v2_, v3_);
        *reinterpret_cast<uint2*>(&xT[i][0]) = r;          // lower half of row i
        if (i >= 4)
            *reinterpret_cast<uint2*>(&xT[i - 4][4]) = r;  // upper half of row i-4
    }

    // preload phase-1 weights + bias
    bf16x8 a0[6];
    #pragma unroll
    for (int c = 0; c < 6; ++c)
        a0[c] = reinterpret_cast<const bf16x8*>(wA0)[c * 64 + l];
    float b00c[4];
    #pragma unroll
    for (int i = 0; i < 4; ++i) b00c[i] = b00[(4 * g + i) & 7];

    __syncthreads();

    // ---- phase 1: fea0 via dual-packed MFMA, 32 positions per 6-MFMA group ----
    {
        const int ngrp = (w < 2) ? 5 : 4;
        const int grp0 = (w < 2) ? 5 * w : 10 + 4 * (w - 2);
        const int rb = 32 * grp0 + lane15 + g;
        bf16x8 bb[6];
        #pragma unroll
        for (int c = 0; c < 6; ++c)
            bb[c] = *reinterpret_cast<const bf16x8*>(&xT[rb + 8 * c][0]);
        #pragma unroll
        for (int it = 0; it < 5; ++it) {
            if (it < ngrp) {
                f32x4 d = {0.f, 0.f, 0.f, 0.f};
                #pragma unroll
                for (int c = 0; c < 6; ++c)
                    d = __builtin_amdgcn_mfma_f32_16x16x32_bf16(a0[c], bb[c], d, 0, 0, 0);
                int s = 32 * (grp0 + it) + lane15 + ((g >= 2) ? 16 : 0);
                int j = p0 - 16 + s;
                bool ok = (unsigned)j <= 8192u;
                float e0 = ok ? d[0] + b00c[0] : 0.f;
                float e1 = ok ? d[1] + b00c[1] : 0.f;
                float e2 = ok ? d[2] + b00c[2] : 0.f;
                float e3 = ok ? d[3] + b00c[3] : 0.f;
                uint2 wv;
                wv.x = cvt_pk_bf16(e0, e1);
                wv.y = cvt_pk_bf16(e2, e3);
                *reinterpret_cast<uint2*>(&f0T[s][4 * (g & 1)]) = wv;
                if (it + 1 < ngrp) {       // slide window: chunks 4,5 -> 0,1
                    bb[0] = bb[4]; bb[1] = bb[5];
                    int nb = rb + 32 * (it + 1);
                    #pragma unroll
                    for (int c = 2; c < 6; ++c)
                        bb[c] = *reinterpret_cast<const bf16x8*>(&xT[nb + 8 * c][0]);
                }
            }
        }
    }

    // preload phase-2 constants
    bf16x8 a1[6];
    #pragma unroll
    for (int c = 0; c < 6; ++c)
        a1[c] = reinterpret_cast<const bf16x8*>(wA1)[c * 64 + l];
    bf16x8 mfrag  = reinterpret_cast<const bf16x8*>(Mp)[b * 64 + l];
    bf16x8 wc0Af  = reinterpret_cast<const bf16x8*>(wc0A)[l];
    float cb1[4], bf2v[4];
    #pragma unroll
    for (int i = 0; i < 4; ++i) {
        int o = 4 * g + i;
        cb1[i] = (o < 8) ? b01[o] : b02[o - 8];
        float inv2 = g2[o] * rsqrtf(v2[o] + 1e-5f);
        bf2v[i] = bt2[o] - m2[o] * inv2;
    }
    // per-lane sparse-q read offsets (q + 2 baked in)
    int qoff[6];
    qoff[0] = 2 * g + 2;  qoff[1] = 9 + g;   qoff[2] = 13 + g;
    qoff[3] = 17 + g;     qoff[4] = 21 + g;  qoff[5] = 26 + 2 * g;
    // shuffle sources for c0 D->B redistribution
    const int s0 = (lane15 + 32 * g) & 63;
    const int s1 = (s0 + 16) & 63;

    __syncthreads();

    // ---- phase 2: fusion (6 sparse chunks) + c0-MFMA + c2-MFMA + store ----
    {
        float* ob = out + (size_t)b * 16 * LL;
        const f32x4 zc = {0.f, 0.f, 0.f, 0.f};
        #pragma unroll
        for (int it = 0; it < 8; ++it) {
            const int gi = 8 * w + it;
            const int rbase = 16 * gi + lane15;
            bf16x8 bb[6];
            #pragma unroll
            for (int c = 0; c < 6; ++c)
                bb[c] = *reinterpret_cast<const bf16x8*>(&f0T[rbase + qoff[c]][0]);
            f32x4 dF = {0.f, 0.f, 0.f, 0.f};
            #pragma unroll
            for (int c = 0; c < 6; ++c)
                dF = __builtin_amdgcn_mfma_f32_16x16x32_bf16(a1[c], bb[c], dF, 0, 0, 0);

            // c0_pre = MFMA(wc0A, [x;1]) : D rows u=4g+i, cols = position
            U4 xu; xu.u.x = 0u; xu.u.y = 0u; xu.u.z = 0u; xu.u.w = 0u;
            if (g == 0) {
                uint2 xr = *reinterpret_cast<const uint2*>(&xT[rbase + 32][0]);
                xu.u.x = xr.x; xu.u.y = xr.y;
                xu.u.z = 0x3f80u;            // k=4 : constant 1.0 (bias slot)
            }
            f32x4 dP = __builtin_amdgcn_mfma_f32_16x16x32_bf16(wc0Af, xu.v, zc, 0, 0, 0);
            unsigned pk0 = cvt_pk_bf16(fmaxf(dP[0], 0.f), fmaxf(dP[1], 0.f));
            unsigned pk1 = cvt_pk_bf16(fmaxf(dP[2], 0.f), fmaxf(dP[3], 0.f));
            // redistribute: lane group g needs u = 8g..8g+7 (from groups 2g, 2g+1)
            U4 uu;
            uu.u.x = __shfl(pk0, s0, 64);
            uu.u.y = __shfl(pk1, s0, 64);
            uu.u.z = __shfl(pk0, s1, 64);
            uu.u.w = __shfl(pk1, s1, 64);
            f32x4 dC = __builtin_amdgcn_mfma_f32_16x16x32_bf16(mfrag, uu.v, zc, 0, 0, 0);

            const int p = p0 + 16 * gi + lane15;
            const bool edge = (p < 1) | (p > LL - 3);
            float* op = ob + p;
            #pragma unroll
            for (int i = 0; i < 4; ++i) {
                int o = 4 * g + i;
                float vf = dF[i] + cb1[i];
                if (o >= 8 && edge) vf = 0.f;
                float c2 = fmaxf(dC[i] + bf2v[i], 0.f);
                op[(size_t)o * LL] = vf + c2;
            }
        }
    }
}

extern "C" void kernel_launch(void* const* d_in, const int* in_sizes, int n_in,
                              void* d_out, int out_size, void* d_ws, size_t ws_size,
                              hipStream_t stream)
{
    const float* x    = (const float*)d_in[0];
    const float* w00  = (const float*)d_in[1];
    const float* b00  = (const float*)d_in[2];
    const float* w01  = (const float*)d_in[3];
    const float* b01  = (const float*)d_in[4];
    const float* w02  = (const float*)d_in[5];
    const float* b02  = (const float*)d_in[6];
    const float* wc1  = (const float*)d_in[7];
    const float* g1   = (const float*)d_in[8];
    const float* bt1  = (const float*)d_in[9];
    const float* m1   = (const float*)d_in[10];
    const float* v1   = (const float*)d_in[11];
    const float* beta = (const float*)d_in[12];
    const float* wc2  = (const float*)d_in[13];
    const float* g2   = (const float*)d_in[14];
    const float* bt2  = (const float*)d_in[15];
    const float* m2   = (const float*)d_in[16];
    const float* v2   = (const float*)d_in[17];

    char* wsb = (char*)d_ws;
    float* partialp       = (float*)wsb;                       // 2,097,152 B
    unsigned short* Mpp   = (unsigned short*)(wsb + 2097152);  // 262,144 B
    unsigned short* wA0p  = (unsigned short*)(wsb + 2359296);  // 6,144 B
    unsigned short* wA1p  = (unsigned short*)(wsb + 2365440);  // 6,144 B
    unsigned short* wc0Ap = (unsigned short*)(wsb + 2371584);  // 1,024 B
    float* o = (float*)d_out;

    hipLaunchKernelGGL(kernA1, dim3(2048), dim3(256), 0, stream,
        x, wc1, g1, bt1, m1, v1, partialp);
    hipLaunchKernelGGL(kernA2, dim3(256), dim3(256), 0, stream,
        partialp, beta, wc2, g2, bt2, m2, v2, w00, w01, w02,
        wc1, g1, bt1, m1, v1, Mpp, wA0p, wA1p, wc0Ap);
    hipLaunchKernelGGL(kernB, dim3(4096), dim3(256), 0, stream,
        x, b00, b01, b02, g2, bt2, m2, v2,
        wA0p, wA1p, wc0Ap, Mpp, o);
}

// Round 7
// 70.813 us; speedup vs baseline: 14.6600x; 1.1456x over previous
//
#include <hip/hip_runtime.h>

#define LL 8192

typedef __attribute__((ext_vector_type(8))) short bf16x8;
typedef __attribute__((ext_vector_type(4))) float f32x4;

union U4 { uint4 u; bf16x8 v; };

__device__ __forceinline__ float4 ld4(const float* p) {
    return *reinterpret_cast<const float4*>(p);
}
__device__ __forceinline__ unsigned short f2bf(float f) {
    union { float f; unsigned u; } v; v.f = f;
    unsigned r = v.u + 0x7fffu + ((v.u >> 16) & 1u);
    return (unsigned short)(r >> 16);
}
__device__ __forceinline__ unsigned cvt_pk_bf16(float lo, float hi) {
    unsigned r;
    asm("v_cvt_pk_bf16_f32 %0, %1, %2" : "=v"(r) : "v"(lo), "v"(hi));
    return r;
}

// ---------------------------------------------------------------------------
// kernA1: Gram of c0 over a 1024-position chunk via MFMA (A-frag == B-frag).
// grid = 256*8, block = 256
// ---------------------------------------------------------------------------
__global__ __launch_bounds__(256) void kernA1(
    const float* __restrict__ x, const float* __restrict__ wc1,
    const float* __restrict__ g1, const float* __restrict__ bt1,
    const float* __restrict__ m1, const float* __restrict__ v1,
    float* __restrict__ partial)
{
    __shared__ float xs[4][1024];                         // 16 KB (reused for gsum)
    __shared__ __align__(16) unsigned short c0f[16384];   // 32 KB frag-slot layout
    __shared__ float wf1[16][4];
    __shared__ float bf1[16];

    const int blk = blockIdx.x;
    const int b = blk >> 3, chunk = blk & 7;
    const int t = threadIdx.x;
    const int w = t >> 6, l = t & 63;
    const float* xb = x + (size_t)b * 4 * LL;
    const int p0 = chunk << 10;

    if (t < 16) {
        float inv = g1[t] * rsqrtf(v1[t] + 1e-5f);
        #pragma unroll
        for (int c = 0; c < 4; ++c) wf1[t][c] = wc1[t * 4 + c] * inv;
        bf1[t] = bt1[t] - m1[t] * inv;
    }
    #pragma unroll
    for (int c = 0; c < 4; ++c) {
        float4 v = ld4(&xb[c * LL + p0 + 4 * t]);
        *reinterpret_cast<float4*>(&xs[c][4 * t]) = v;
    }
    __syncthreads();

    {
        const int u = t & 15, pblk = t >> 4;
        float w0 = wf1[u][0], w1 = wf1[u][1], w2 = wf1[u][2], w3 = wf1[u][3];
        float bu = bf1[u];
        #pragma unroll 4
        for (int pp = 0; pp < 64; pp += 2) {
            int p = (pblk << 6) + pp;
            float c00 = fmaxf(bu + w0 * xs[0][p] + w1 * xs[1][p]
                                 + w2 * xs[2][p] + w3 * xs[3][p], 0.f);
            float c01 = fmaxf(bu + w0 * xs[0][p + 1] + w1 * xs[1][p + 1]
                                 + w2 * xs[2][p + 1] + w3 * xs[3][p + 1], 0.f);
            int slot = ((p >> 5) << 6) + (((p >> 3) & 3) << 4) + u;
            *reinterpret_cast<unsigned*>(&c0f[slot * 8 + (p & 7)]) =
                cvt_pk_bf16(c00, c01);
        }
    }
    __syncthreads();

    f32x4 acc = {0.f, 0.f, 0.f, 0.f};
    #pragma unroll
    for (int m = 0; m < 8; ++m) {
        int slot = (w * 8 + m) * 64 + l;
        bf16x8 fr = *reinterpret_cast<const bf16x8*>(&c0f[slot * 8]);
        acc = __builtin_amdgcn_mfma_f32_16x16x32_bf16(fr, fr, acc, 0, 0, 0);
    }

    float* gsumf = &xs[0][0];
    {
        int col = l & 15, rg = l >> 4;
        #pragma unroll
        for (int i = 0; i < 4; ++i)
            gsumf[w * 256 + (rg * 4 + i) * 16 + col] = acc[i];
    }
    __syncthreads();
    partial[(size_t)(b * 8 + chunk) * 256 + t] =
        gsumf[t] + gsumf[256 + t] + gsumf[512 + t] + gsumf[768 + t];
}

// ---------------------------------------------------------------------------
// kernA2: reduce partials -> softmax -> M -> Mp; block 0 also packs weights.
// grid 256
// ---------------------------------------------------------------------------
__global__ __launch_bounds__(256) void kernA2(
    const float* __restrict__ partial, const float* __restrict__ beta_cam,
    const float* __restrict__ wc2, const float* __restrict__ g2,
    const float* __restrict__ bt2, const float* __restrict__ m2,
    const float* __restrict__ v2,
    const float* __restrict__ w00, const float* __restrict__ w01,
    const float* __restrict__ w02,
    const float* __restrict__ wc1, const float* __restrict__ g1,
    const float* __restrict__ bt1, const float* __restrict__ m1,
    const float* __restrict__ v1,
    unsigned short* __restrict__ Mp,
    unsigned short* __restrict__ wA0, unsigned short* __restrict__ wA1,
    unsigned short* __restrict__ wc0A)
{
    __shared__ float gram[16][16];
    __shared__ float attn[16][16];
    __shared__ float Msh[16][16];
    const int b = blockIdx.x, t = threadIdx.x;

    if (b == 0) {   // pack conv weights into MFMA A-fragment order
        // ---- wA0: fea0 dual-position packing (6 chunks) ----
        for (int i = t; i < 384; i += 256) {
            const int c = i >> 6, li = i & 63;
            const int row = li & 15, g = li >> 4;
            #pragma unroll
            for (int j = 0; j < 8; ++j) {
                int ch = j & 3;
                int T = 8 * c + g + ((j >= 4) ? 4 : 0);
                float v = 0.f;
                if (row < 8) {
                    if (T < 32) v = w00[(row * 4 + ch) * 32 + T];
                } else {
                    int tt = T - 16;
                    if (tt >= 0) v = w00[((row - 8) * 4 + ch) * 32 + tt];
                }
                wA0[(c * 64 + li) * 8 + j] = f2bf(v);
            }
        }
        // ---- wA1: fusion dense packing (8 chunks, q = 4c+g) ----
        for (int i = t; i < 512; i += 256) {
            const int c = i >> 6, li = i & 63;
            const int row = li & 15, g = li >> 4;
            int q = 4 * c + g;
            #pragma unroll
            for (int j = 0; j < 8; ++j) {
                float v = 0.f;
                if (row < 8) {
                    if (q >= 7 && q <= 22) v = w01[(row * 8 + j) * 16 + (q - 7)];
                } else {
                    if (!(q & 1)) v = w02[((row - 8) * 8 + j) * 16 + (q >> 1)];
                }
                wA1[(c * 64 + li) * 8 + j] = f2bf(v);
            }
        }
        // ---- wc0A: c0 1x1-conv A-frag, bias folded at k=4 ----
        if (t < 64) {
            int u = t & 15, gg = t >> 4;
            float inv = g1[u] * rsqrtf(v1[u] + 1e-5f);
            #pragma unroll
            for (int j = 0; j < 8; ++j) {
                float v = 0.f;
                if (gg == 0) {
                    if (j < 4) v = wc1[u * 4 + j] * inv;
                    else if (j == 4) v = bt1[u] - m1[u] * inv;
                }
                wc0A[t * 8 + j] = f2bf(v);
            }
        }
    }

    const float* P = partial + (size_t)b * 2048;
    float s = 0.f;
    #pragma unroll
    for (int k = 0; k < 8; ++k) s += P[k * 256 + t];
    gram[t >> 4][t & 15] = s;
    __syncthreads();
    {
        const float beta = beta_cam[0];
        int d = t & 15;
        float gv = gram[t >> 4][d];
        float rm = gv;
        #pragma unroll
        for (int m = 1; m < 16; m <<= 1) rm = fmaxf(rm, __shfl_xor(rm, m, 64));
        float a = rm - gv;
        float am = a;
        #pragma unroll
        for (int m = 1; m < 16; m <<= 1) am = fmaxf(am, __shfl_xor(am, m, 64));
        float e = __expf(a - am);
        float ssum = e;
        #pragma unroll
        for (int m = 1; m < 16; m <<= 1) ssum += __shfl_xor(ssum, m, 64);
        attn[t >> 4][d] = beta * e / ssum;
    }
    __syncthreads();
    {
        int o = t >> 4, u = t & 15;
        float inv2 = g2[o] * rsqrtf(v2[o] + 1e-5f);
        float sm = wc2[o * 16 + u];
        #pragma unroll
        for (int d = 0; d < 16; ++d) sm += wc2[o * 16 + d] * attn[d][u];
        Msh[o][u] = sm * inv2;
    }
    __syncthreads();
    for (int idx = t; idx < 512; idx += 256) {
        int li = idx >> 3, j = idx & 7;
        int k = 8 * (li >> 4) + j, o = li & 15;
        float v = (k < 16) ? Msh[o][k] : 0.f;
        Mp[(size_t)b * 512 + idx] = f2bf(v);
    }
}

// ---------------------------------------------------------------------------
// kernB: MFMA conv pipeline; interior fast path, bias-seeded accumulators,
// immediate-offset LDS/store addressing, dense sliding phase 2.
// grid 256*16, block 256 (4 waves), T=512 positions per block.
// ---------------------------------------------------------------------------
__global__ __launch_bounds__(256, 4) void kernB(
    const float* __restrict__ x,
    const float* __restrict__ b00, const float* __restrict__ b01,
    const float* __restrict__ b02,
    const float* __restrict__ g2, const float* __restrict__ bt2,
    const float* __restrict__ m2, const float* __restrict__ v2,
    const unsigned short* __restrict__ wA0, const unsigned short* __restrict__ wA1,
    const unsigned short* __restrict__ wc0A,
    const unsigned short* __restrict__ Mp, float* __restrict__ out)
{
    // xT row i: elems 0..3 = x[0..3][p0-32+i], elems 4..7 = x[0..3][p0-32+i+4]
    __shared__ __align__(16) unsigned short xT[608][8];
    __shared__ __align__(16) unsigned short f0T[576][8];  // slot s <-> j = p0-16+s

    const int blk = blockIdx.x;
    const int b  = blk >> 4;
    const int p0 = (blk & 15) << 9;
    const int t  = threadIdx.x;
    const int w  = t >> 6, l = t & 63;
    const int lane15 = l & 15, g = l >> 4;
    const float* xb = x + (size_t)b * 4 * LL;
    const bool intr = (p0 != 0) && (p0 != 15 * 512);

    // ---- stage xT: one load per row -> row i lower + row i-4 upper ----
    if (intr) {
        for (int i = t; i < 608; i += 256) {
            int xp = p0 - 32 + i;
            float v0  = xb[0 * LL + xp];
            float v1_ = xb[1 * LL + xp];
            float v2_ = xb[2 * LL + xp];
            float v3_ = xb[3 * LL + xp];
            uint2 r;
            r.x = cvt_pk_bf16(v0, v1_);
            r.y = cvt_pk_bf16(v2_, v3_);
            *reinterpret_cast<uint2*>(&xT[i][0]) = r;
            if (i >= 4)
                *reinterpret_cast<uint2*>(&xT[i - 4][4]) = r;
        }
    } else {
        for (int i = t; i < 608; i += 256) {
            int xp = p0 - 32 + i;
            bool ok = (unsigned)xp < 8192u;
            float v0  = ok ? xb[0 * LL + xp] : 0.f;
            float v1_ = ok ? xb[1 * LL + xp] : 0.f;
            float v2_ = ok ? xb[2 * LL + xp] : 0.f;
            float v3_ = ok ? xb[3 * LL + xp] : 0.f;
            uint2 r;
            r.x = cvt_pk_bf16(v0, v1_);
            r.y = cvt_pk_bf16(v2_, v3_);
            *reinterpret_cast<uint2*>(&xT[i][0]) = r;
            if (i >= 4)
                *reinterpret_cast<uint2*>(&xT[i - 4][4]) = r;
        }
    }

    // preload phase-1 weights + bias
    bf16x8 a0[6];
    #pragma unroll
    for (int c = 0; c < 6; ++c)
        a0[c] = reinterpret_cast<const bf16x8*>(wA0)[c * 64 + l];
    float b00c[4];
    #pragma unroll
    for (int i = 0; i < 4; ++i) b00c[i] = b00[(4 * g + i) & 7];

    __syncthreads();

    // ---- phase 1: fea0 via dual-packed MFMA, 32 positions per 6-MFMA group ----
    {
        const int ngrp = (w < 2) ? 5 : 4;
        const int grp0 = (w < 2) ? 5 * w : 10 + 4 * (w - 2);
        const unsigned short* xrow = &xT[32 * grp0 + lane15 + g][0];
        const int s_base = 32 * grp0 + lane15 + ((g >= 2) ? 16 : 0);
        unsigned short* wp = &f0T[s_base][4 * (g & 1)];
        bf16x8 bb[6];
        #pragma unroll
        for (int c = 0; c < 6; ++c)
            bb[c] = *reinterpret_cast<const bf16x8*>(xrow + 64 * c);
        #pragma unroll
        for (int it = 0; it < 5; ++it) {
            if (it < ngrp) {
                f32x4 d = {b00c[0], b00c[1], b00c[2], b00c[3]};
                #pragma unroll
                for (int c = 0; c < 6; ++c)
                    d = __builtin_amdgcn_mfma_f32_16x16x32_bf16(a0[c], bb[c], d, 0, 0, 0);
                float e0 = d[0], e1 = d[1], e2 = d[2], e3 = d[3];
                if (!intr) {
                    int j = p0 - 16 + s_base + 32 * it;
                    bool ok = (unsigned)j <= 8192u;
                    e0 = ok ? e0 : 0.f;  e1 = ok ? e1 : 0.f;
                    e2 = ok ? e2 : 0.f;  e3 = ok ? e3 : 0.f;
                }
                uint2 wv;
                wv.x = cvt_pk_bf16(e0, e1);
                wv.y = cvt_pk_bf16(e2, e3);
                *reinterpret_cast<uint2*>(wp + 256 * it) = wv;
                if (it + 1 < ngrp) {       // slide window: chunks 4,5 -> 0,1
                    bb[0] = bb[4]; bb[1] = bb[5];
                    #pragma unroll
                    for (int c = 2; c < 6; ++c)
                        bb[c] = *reinterpret_cast<const bf16x8*>(
                            xrow + 32 * 8 * (it + 1) + 64 * c);
                }
            }
        }
    }

    // preload phase-2 constants
    bf16x8 a1[8];
    #pragma unroll
    for (int c = 0; c < 8; ++c)
        a1[c] = reinterpret_cast<const bf16x8*>(wA1)[c * 64 + l];
    bf16x8 mfrag  = reinterpret_cast<const bf16x8*>(Mp)[b * 64 + l];
    bf16x8 wc0Af  = reinterpret_cast<const bf16x8*>(wc0A)[l];
    float cb1[4], bf2v[4];
    #pragma unroll
    for (int i = 0; i < 4; ++i) {
        int o = 4 * g + i;
        cb1[i] = (o < 8) ? b01[o] : b02[o - 8];
        float inv2 = g2[o] * rsqrtf(v2[o] + 1e-5f);
        bf2v[i] = bt2[o] - m2[o] * inv2;
    }
    const unsigned mask1 = (g == 0) ? 0x3f80u : 0u;
    const bool g0 = (g == 0);
    // shuffle sources for c0 D->B redistribution
    const int s0 = (lane15 + 32 * g) & 63;
    const int s1 = (s0 + 16) & 63;

    __syncthreads();

    // ---- phase 2: fusion (dense slide) + c0-MFMA + c2-MFMA + store ----
    {
        const int gi0 = 8 * w;
        const unsigned short* frow = &f0T[16 * gi0 + lane15 + g + 2][0];
        const unsigned short* xrow2 = &xT[16 * gi0 + lane15 + 32][0];
        const size_t obase = (size_t)b * 16 * LL + p0 + 16 * gi0 + lane15;
        float* o0 = out + obase + (size_t)(4 * g + 0) * LL;
        float* o1 = out + obase + (size_t)(4 * g + 1) * LL;
        float* o2 = out + obase + (size_t)(4 * g + 2) * LL;
        float* o3 = out + obase + (size_t)(4 * g + 3) * LL;
        const f32x4 zc = {0.f, 0.f, 0.f, 0.f};

        bf16x8 bb[8];
        #pragma unroll
        for (int c = 0; c < 8; ++c)
            bb[c] = *reinterpret_cast<const bf16x8*>(frow + 32 * c);
        #pragma unroll
        for (int it = 0; it < 8; ++it) {
            f32x4 dF = {cb1[0], cb1[1], cb1[2], cb1[3]};
            #pragma unroll
            for (int c = 0; c < 8; ++c)
                dF = __builtin_amdgcn_mfma_f32_16x16x32_bf16(a1[c], bb[c], dF, 0, 0, 0);

            // c0_pre = MFMA(wc0A, [x;1]) : D rows u=4g+i, cols = position
            uint2 xr = *reinterpret_cast<const uint2*>(xrow2 + 128 * it);
            U4 xu;
            xu.u.x = g0 ? xr.x : 0u;
            xu.u.y = g0 ? xr.y : 0u;
            xu.u.z = mask1;
            xu.u.w = 0u;
            f32x4 dP = __builtin_amdgcn_mfma_f32_16x16x32_bf16(wc0Af, xu.v, zc, 0, 0, 0);
            unsigned pk0 = cvt_pk_bf16(fmaxf(dP[0], 0.f), fmaxf(dP[1], 0.f));
            unsigned pk1 = cvt_pk_bf16(fmaxf(dP[2], 0.f), fmaxf(dP[3], 0.f));
            U4 uu;
            uu.u.x = __shfl(pk0, s0, 64);
            uu.u.y = __shfl(pk1, s0, 64);
            uu.u.z = __shfl(pk0, s1, 64);
            uu.u.w = __shfl(pk1, s1, 64);
            f32x4 dC = {bf2v[0], bf2v[1], bf2v[2], bf2v[3]};
            dC = __builtin_amdgcn_mfma_f32_16x16x32_bf16(mfrag, uu.v, dC, 0, 0, 0);

            float c20 = fmaxf(dC[0], 0.f), c21 = fmaxf(dC[1], 0.f);
            float c22 = fmaxf(dC[2], 0.f), c23 = fmaxf(dC[3], 0.f);
            float r0 = dF[0] + c20, r1 = dF[1] + c21;
            float r2 = dF[2] + c22, r3 = dF[3] + c23;
            if (!intr) {
                int p = p0 + 16 * (gi0 + it) + lane15;
                if (((p < 1) | (p > LL - 3)) && g >= 2) {
                    r0 = c20; r1 = c21; r2 = c22; r3 = c23;
                }
            }
            o0[16 * it] = r0;
            o1[16 * it] = r1;
            o2[16 * it] = r2;
            o3[16 * it] = r3;

            if (it < 7) {       // slide: chunks 4..7 -> 0..3, read 4 new
                bb[0] = bb[4]; bb[1] = bb[5]; bb[2] = bb[6]; bb[3] = bb[7];
                #pragma unroll
                for (int c = 4; c < 8; ++c)
                    bb[c] = *reinterpret_cast<const bf16x8*>(
                        frow + 16 * 8 * (it + 1) + 32 * c);
            }
        }
    }
}

extern "C" void kernel_launch(void* const* d_in, const int* in_sizes, int n_in,
                              void* d_out, int out_size, void* d_ws, size_t ws_size,
                              hipStream_t stream)
{
    const float* x    = (const float*)d_in[0];
    const float* w00  = (const float*)d_in[1];
    const float* b00  = (const float*)d_in[2];
    const float* w01  = (const float*)d_in[3];
    const float* b01  = (const float*)d_in[4];
    const float* w02  = (const float*)d_in[5];
    const float* b02  = (const float*)d_in[6];
    const float* wc1  = (const float*)d_in[7];
    const float* g1   = (const float*)d_in[8];
    const float* bt1  = (const float*)d_in[9];
    const float* m1   = (const float*)d_in[10];
    const float* v1   = (const float*)d_in[11];
    const float* beta = (const float*)d_in[12];
    const float* wc2  = (const float*)d_in[13];
    const float* g2   = (const float*)d_in[14];
    const float* bt2  = (const float*)d_in[15];
    const float* m2   = (const float*)d_in[16];
    const float* v2   = (const float*)d_in[17];

    char* wsb = (char*)d_ws;
    float* partialp       = (float*)wsb;                       // 2,097,152 B
    unsigned short* Mpp   = (unsigned short*)(wsb + 2097152);  // 262,144 B
    unsigned short* wA0p  = (unsigned short*)(wsb + 2359296);  // 6,144 B
    unsigned short* wA1p  = (unsigned short*)(wsb + 2365440);  // 8,192 B
    unsigned short* wc0Ap = (unsigned short*)(wsb + 2373632);  // 1,024 B
    float* o = (float*)d_out;

    hipLaunchKernelGGL(kernA1, dim3(2048), dim3(256), 0, stream,
        x, wc1, g1, bt1, m1, v1, partialp);
    hipLaunchKernelGGL(kernA2, dim3(256), dim3(256), 0, stream,
        partialp, beta, wc2, g2, bt2, m2, v2, w00, w01, w02,
        wc1, g1, bt1, m1, v1, Mpp, wA0p, wA1p, wc0Ap);
    hipLaunchKernelGGL(kernB, dim3(4096), dim3(256), 0, stream,
        x, b00, b01, b02, g2, bt2, m2, v2,
        wA0p, wA1p, wc0Ap, Mpp, o);
}

// Round 8
// 65.832 us; speedup vs baseline: 15.7691x; 1.0757x over previous
//
#include <hip/hip_runtime.h>

#define LL 8192

typedef __attribute__((ext_vector_type(8))) short bf16x8;
typedef __attribute__((ext_vector_type(4))) float f32x4;

union U4 { uint4 u; bf16x8 v; };

__device__ __forceinline__ float4 ld4(const float* p) {
    return *reinterpret_cast<const float4*>(p);
}
__device__ __forceinline__ unsigned short f2bf(float f) {
    union { float f; unsigned u; } v; v.f = f;
    unsigned r = v.u + 0x7fffu + ((v.u >> 16) & 1u);
    return (unsigned short)(r >> 16);
}
__device__ __forceinline__ unsigned cvt_pk_bf16(float lo, float hi) {
    unsigned r;
    asm("v_cvt_pk_bf16_f32 %0, %1, %2" : "=v"(r) : "v"(lo), "v"(hi));
    return r;
}

// ---------------------------------------------------------------------------
// kernA1: Gram of c0 over a 1024-position chunk via MFMA (A-frag == B-frag).
// Register-direct c0: no x staging in LDS; 16 ds_write_b64/thread total.
// grid = 256*8, block = 256
// ---------------------------------------------------------------------------
__global__ __launch_bounds__(256) void kernA1(
    const float* __restrict__ x, const float* __restrict__ wc1,
    const float* __restrict__ g1, const float* __restrict__ bt1,
    const float* __restrict__ m1, const float* __restrict__ v1,
    float* __restrict__ partial)
{
    __shared__ __align__(16) unsigned short c0f[16384];   // 32 KB frag-slot layout
    __shared__ float gsum[1024];                          // 4 KB

    const int blk = blockIdx.x;
    const int b = blk >> 3, chunk = blk & 7;
    const int t = threadIdx.x;
    const int w = t >> 6, l = t & 63;
    const float* xb = x + (size_t)b * 4 * LL;
    const int p0 = chunk << 10;

    // thread t owns chunk-local positions p = 4t .. 4t+3, all 4 channels
    const float4 x0 = ld4(&xb[0 * LL + p0 + 4 * t]);
    const float4 x1 = ld4(&xb[1 * LL + p0 + 4 * t]);
    const float4 x2 = ld4(&xb[2 * LL + p0 + 4 * t]);
    const float4 x3 = ld4(&xb[3 * LL + p0 + 4 * t]);

    // frag-slot layout: slot = (p>>5)*64 + ((p>>3)&3)*16 + u, elem = p&7
    const int p = 4 * t;
    unsigned short* dst =
        &c0f[(((p >> 5) << 6) + (((p >> 3) & 3) << 4)) * 8 + (p & 7)];
    #pragma unroll
    for (int u = 0; u < 16; ++u) {
        float inv = g1[u] * rsqrtf(v1[u] + 1e-5f);
        float w0 = wc1[u * 4 + 0] * inv, w1 = wc1[u * 4 + 1] * inv;
        float w2 = wc1[u * 4 + 2] * inv, w3 = wc1[u * 4 + 3] * inv;
        float bu = bt1[u] - m1[u] * inv;
        float ca = fmaxf(bu + w0 * x0.x + w1 * x1.x + w2 * x2.x + w3 * x3.x, 0.f);
        float cb = fmaxf(bu + w0 * x0.y + w1 * x1.y + w2 * x2.y + w3 * x3.y, 0.f);
        float cc = fmaxf(bu + w0 * x0.z + w1 * x1.z + w2 * x2.z + w3 * x3.z, 0.f);
        float cd = fmaxf(bu + w0 * x0.w + w1 * x1.w + w2 * x2.w + w3 * x3.w, 0.f);
        uint2 pk;
        pk.x = cvt_pk_bf16(ca, cb);
        pk.y = cvt_pk_bf16(cc, cd);
        *reinterpret_cast<uint2*>(dst + u * 8) = pk;
    }
    __syncthreads();

    // Gram: wave w covers positions 256w..256w+255 -> 8 MFMAs, frag = one b128
    f32x4 acc = {0.f, 0.f, 0.f, 0.f};
    #pragma unroll
    for (int m = 0; m < 8; ++m) {
        int slot = (w * 8 + m) * 64 + l;
        bf16x8 fr = *reinterpret_cast<const bf16x8*>(&c0f[slot * 8]);
        acc = __builtin_amdgcn_mfma_f32_16x16x32_bf16(fr, fr, acc, 0, 0, 0);
    }

    {
        int col = l & 15, rg = l >> 4;
        #pragma unroll
        for (int i = 0; i < 4; ++i)
            gsum[w * 256 + (rg * 4 + i) * 16 + col] = acc[i];
    }
    __syncthreads();
    partial[(size_t)(b * 8 + chunk) * 256 + t] =
        gsum[t] + gsum[256 + t] + gsum[512 + t] + gsum[768 + t];
}

// ---------------------------------------------------------------------------
// kernA2: reduce partials -> softmax -> M -> Mp; block 0 also packs weights.
// grid 256
// ---------------------------------------------------------------------------
__global__ __launch_bounds__(256) void kernA2(
    const float* __restrict__ partial, const float* __restrict__ beta_cam,
    const float* __restrict__ wc2, const float* __restrict__ g2,
    const float* __restrict__ bt2, const float* __restrict__ m2,
    const float* __restrict__ v2,
    const float* __restrict__ w00, const float* __restrict__ w01,
    const float* __restrict__ w02,
    const float* __restrict__ wc1, const float* __restrict__ g1,
    const float* __restrict__ bt1, const float* __restrict__ m1,
    const float* __restrict__ v1,
    unsigned short* __restrict__ Mp,
    unsigned short* __restrict__ wA0, unsigned short* __restrict__ wA1,
    unsigned short* __restrict__ wc0A)
{
    __shared__ float gram[16][16];
    __shared__ float attn[16][16];
    __shared__ float Msh[16][16];
    const int b = blockIdx.x, t = threadIdx.x;

    if (b == 0) {   // pack conv weights into MFMA A-fragment order
        // ---- wA0: fea0 dual-position packing (6 chunks) ----
        for (int i = t; i < 384; i += 256) {
            const int c = i >> 6, li = i & 63;
            const int row = li & 15, g = li >> 4;
            #pragma unroll
            for (int j = 0; j < 8; ++j) {
                int ch = j & 3;
                int T = 8 * c + g + ((j >= 4) ? 4 : 0);
                float v = 0.f;
                if (row < 8) {
                    if (T < 32) v = w00[(row * 4 + ch) * 32 + T];
                } else {
                    int tt = T - 16;
                    if (tt >= 0) v = w00[((row - 8) * 4 + ch) * 32 + tt];
                }
                wA0[(c * 64 + li) * 8 + j] = f2bf(v);
            }
        }
        // ---- wA1: fusion dense packing (8 chunks, q = 4c+g) ----
        for (int i = t; i < 512; i += 256) {
            const int c = i >> 6, li = i & 63;
            const int row = li & 15, g = li >> 4;
            int q = 4 * c + g;
            #pragma unroll
            for (int j = 0; j < 8; ++j) {
                float v = 0.f;
                if (row < 8) {
                    if (q >= 7 && q <= 22) v = w01[(row * 8 + j) * 16 + (q - 7)];
                } else {
                    if (!(q & 1)) v = w02[((row - 8) * 8 + j) * 16 + (q >> 1)];
                }
                wA1[(c * 64 + li) * 8 + j] = f2bf(v);
            }
        }
        // ---- wc0A: c0 1x1-conv A-frag, bias folded at k=4 ----
        if (t < 64) {
            int u = t & 15, gg = t >> 4;
            float inv = g1[u] * rsqrtf(v1[u] + 1e-5f);
            #pragma unroll
            for (int j = 0; j < 8; ++j) {
                float v = 0.f;
                if (gg == 0) {
                    if (j < 4) v = wc1[u * 4 + j] * inv;
                    else if (j == 4) v = bt1[u] - m1[u] * inv;
                }
                wc0A[t * 8 + j] = f2bf(v);
            }
        }
    }

    const float* P = partial + (size_t)b * 2048;
    float s = 0.f;
    #pragma unroll
    for (int k = 0; k < 8; ++k) s += P[k * 256 + t];
    gram[t >> 4][t & 15] = s;
    __syncthreads();
    {
        const float beta = beta_cam[0];
        int d = t & 15;
        float gv = gram[t >> 4][d];
        float rm = gv;
        #pragma unroll
        for (int m = 1; m < 16; m <<= 1) rm = fmaxf(rm, __shfl_xor(rm, m, 64));
        float a = rm - gv;
        float am = a;
        #pragma unroll
        for (int m = 1; m < 16; m <<= 1) am = fmaxf(am, __shfl_xor(am, m, 64));
        float e = __expf(a - am);
        float ssum = e;
        #pragma unroll
        for (int m = 1; m < 16; m <<= 1) ssum += __shfl_xor(ssum, m, 64);
        attn[t >> 4][d] = beta * e / ssum;
    }
    __syncthreads();
    {
        int o = t >> 4, u = t & 15;
        float inv2 = g2[o] * rsqrtf(v2[o] + 1e-5f);
        float sm = wc2[o * 16 + u];
        #pragma unroll
        for (int d = 0; d < 16; ++d) sm += wc2[o * 16 + d] * attn[d][u];
        Msh[o][u] = sm * inv2;
    }
    __syncthreads();
    for (int idx = t; idx < 512; idx += 256) {
        int li = idx >> 3, j = idx & 7;
        int k = 8 * (li >> 4) + j, o = li & 15;
        float v = (k < 16) ? Msh[o][k] : 0.f;
        Mp[(size_t)b * 512 + idx] = f2bf(v);
    }
}

// ---------------------------------------------------------------------------
// kernB: MFMA conv pipeline; interior fast path, bias-seeded accumulators,
// immediate-offset LDS/store addressing, dense sliding phase 2.
// grid 256*16, block 256 (4 waves), T=512 positions per block.
// ---------------------------------------------------------------------------
__global__ __launch_bounds__(256, 4) void kernB(
    const float* __restrict__ x,
    const float* __restrict__ b00, const float* __restrict__ b01,
    const float* __restrict__ b02,
    const float* __restrict__ g2, const float* __restrict__ bt2,
    const float* __restrict__ m2, const float* __restrict__ v2,
    const unsigned short* __restrict__ wA0, const unsigned short* __restrict__ wA1,
    const unsigned short* __restrict__ wc0A,
    const unsigned short* __restrict__ Mp, float* __restrict__ out)
{
    // xT row i: elems 0..3 = x[0..3][p0-32+i], elems 4..7 = x[0..3][p0-32+i+4]
    __shared__ __align__(16) unsigned short xT[608][8];
    __shared__ __align__(16) unsigned short f0T[576][8];  // slot s <-> j = p0-16+s

    const int blk = blockIdx.x;
    const int b  = blk >> 4;
    const int p0 = (blk & 15) << 9;
    const int t  = threadIdx.x;
    const int w  = t >> 6, l = t & 63;
    const int lane15 = l & 15, g = l >> 4;
    const float* xb = x + (size_t)b * 4 * LL;
    const bool intr = (p0 != 0) && (p0 != 15 * 512);

    // ---- stage xT: one load per row -> row i lower + row i-4 upper ----
    if (intr) {
        for (int i = t; i < 608; i += 256) {
            int xp = p0 - 32 + i;
            float v0  = xb[0 * LL + xp];
            float v1_ = xb[1 * LL + xp];
            float v2_ = xb[2 * LL + xp];
            float v3_ = xb[3 * LL + xp];
            uint2 r;
            r.x = cvt_pk_bf16(v0, v1_);
            r.y = cvt_pk_bf16(v2_, v3_);
            *reinterpret_cast<uint2*>(&xT[i][0]) = r;
            if (i >= 4)
                *reinterpret_cast<uint2*>(&xT[i - 4][4]) = r;
        }
    } else {
        for (int i = t; i < 608; i += 256) {
            int xp = p0 - 32 + i;
            bool ok = (unsigned)xp < 8192u;
            float v0  = ok ? xb[0 * LL + xp] : 0.f;
            float v1_ = ok ? xb[1 * LL + xp] : 0.f;
            float v2_ = ok ? xb[2 * LL + xp] : 0.f;
            float v3_ = ok ? xb[3 * LL + xp] : 0.f;
            uint2 r;
            r.x = cvt_pk_bf16(v0, v1_);
            r.y = cvt_pk_bf16(v2_, v3_);
            *reinterpret_cast<uint2*>(&xT[i][0]) = r;
            if (i >= 4)
                *reinterpret_cast<uint2*>(&xT[i - 4][4]) = r;
        }
    }

    // preload phase-1 weights + bias
    bf16x8 a0[6];
    #pragma unroll
    for (int c = 0; c < 6; ++c)
        a0[c] = reinterpret_cast<const bf16x8*>(wA0)[c * 64 + l];
    float b00c[4];
    #pragma unroll
    for (int i = 0; i < 4; ++i) b00c[i] = b00[(4 * g + i) & 7];

    __syncthreads();

    // ---- phase 1: fea0 via dual-packed MFMA, 32 positions per 6-MFMA group ----
    {
        const int ngrp = (w < 2) ? 5 : 4;
        const int grp0 = (w < 2) ? 5 * w : 10 + 4 * (w - 2);
        const unsigned short* xrow = &xT[32 * grp0 + lane15 + g][0];
        const int s_base = 32 * grp0 + lane15 + ((g >= 2) ? 16 : 0);
        unsigned short* wp = &f0T[s_base][4 * (g & 1)];
        bf16x8 bb[6];
        #pragma unroll
        for (int c = 0; c < 6; ++c)
            bb[c] = *reinterpret_cast<const bf16x8*>(xrow + 64 * c);
        #pragma unroll
        for (int it = 0; it < 5; ++it) {
            if (it < ngrp) {
                f32x4 d = {b00c[0], b00c[1], b00c[2], b00c[3]};
                #pragma unroll
                for (int c = 0; c < 6; ++c)
                    d = __builtin_amdgcn_mfma_f32_16x16x32_bf16(a0[c], bb[c], d, 0, 0, 0);
                float e0 = d[0], e1 = d[1], e2 = d[2], e3 = d[3];
                if (!intr) {
                    int j = p0 - 16 + s_base + 32 * it;
                    bool ok = (unsigned)j <= 8192u;
                    e0 = ok ? e0 : 0.f;  e1 = ok ? e1 : 0.f;
                    e2 = ok ? e2 : 0.f;  e3 = ok ? e3 : 0.f;
                }
                uint2 wv;
                wv.x = cvt_pk_bf16(e0, e1);
                wv.y = cvt_pk_bf16(e2, e3);
                *reinterpret_cast<uint2*>(wp + 256 * it) = wv;
                if (it + 1 < ngrp) {       // slide window: chunks 4,5 -> 0,1
                    bb[0] = bb[4]; bb[1] = bb[5];
                    #pragma unroll
                    for (int c = 2; c < 6; ++c)
                        bb[c] = *reinterpret_cast<const bf16x8*>(
                            xrow + 32 * 8 * (it + 1) + 64 * c);
                }
            }
        }
    }

    // preload phase-2 constants
    bf16x8 a1[8];
    #pragma unroll
    for (int c = 0; c < 8; ++c)
        a1[c] = reinterpret_cast<const bf16x8*>(wA1)[c * 64 + l];
    bf16x8 mfrag  = reinterpret_cast<const bf16x8*>(Mp)[b * 64 + l];
    bf16x8 wc0Af  = reinterpret_cast<const bf16x8*>(wc0A)[l];
    float cb1[4], bf2v[4];
    #pragma unroll
    for (int i = 0; i < 4; ++i) {
        int o = 4 * g + i;
        cb1[i] = (o < 8) ? b01[o] : b02[o - 8];
        float inv2 = g2[o] * rsqrtf(v2[o] + 1e-5f);
        bf2v[i] = bt2[o] - m2[o] * inv2;
    }
    const unsigned mask1 = (g == 0) ? 0x3f80u : 0u;
    const bool g0 = (g == 0);
    // shuffle sources for c0 D->B redistribution
    const int s0 = (lane15 + 32 * g) & 63;
    const int s1 = (s0 + 16) & 63;

    __syncthreads();

    // ---- phase 2: fusion (dense slide) + c0-MFMA + c2-MFMA + store ----
    {
        const int gi0 = 8 * w;
        const unsigned short* frow = &f0T[16 * gi0 + lane15 + g + 2][0];
        const unsigned short* xrow2 = &xT[16 * gi0 + lane15 + 32][0];
        const size_t obase = (size_t)b * 16 * LL + p0 + 16 * gi0 + lane15;
        float* o0 = out + obase + (size_t)(4 * g + 0) * LL;
        float* o1 = out + obase + (size_t)(4 * g + 1) * LL;
        float* o2 = out + obase + (size_t)(4 * g + 2) * LL;
        float* o3 = out + obase + (size_t)(4 * g + 3) * LL;
        const f32x4 zc = {0.f, 0.f, 0.f, 0.f};

        bf16x8 bb[8];
        #pragma unroll
        for (int c = 0; c < 8; ++c)
            bb[c] = *reinterpret_cast<const bf16x8*>(frow + 32 * c);
        #pragma unroll
        for (int it = 0; it < 8; ++it) {
            f32x4 dF = {cb1[0], cb1[1], cb1[2], cb1[3]};
            #pragma unroll
            for (int c = 0; c < 8; ++c)
                dF = __builtin_amdgcn_mfma_f32_16x16x32_bf16(a1[c], bb[c], dF, 0, 0, 0);

            // c0_pre = MFMA(wc0A, [x;1]) : D rows u=4g+i, cols = position
            uint2 xr = *reinterpret_cast<const uint2*>(xrow2 + 128 * it);
            U4 xu;
            xu.u.x = g0 ? xr.x : 0u;
            xu.u.y = g0 ? xr.y : 0u;
            xu.u.z = mask1;
            xu.u.w = 0u;
            f32x4 dP = __builtin_amdgcn_mfma_f32_16x16x32_bf16(wc0Af, xu.v, zc, 0, 0, 0);
            unsigned pk0 = cvt_pk_bf16(fmaxf(dP[0], 0.f), fmaxf(dP[1], 0.f));
            unsigned pk1 = cvt_pk_bf16(fmaxf(dP[2], 0.f), fmaxf(dP[3], 0.f));
            U4 uu;
            uu.u.x = __shfl(pk0, s0, 64);
            uu.u.y = __shfl(pk1, s0, 64);
            uu.u.z = __shfl(pk0, s1, 64);
            uu.u.w = __shfl(pk1, s1, 64);
            f32x4 dC = {bf2v[0], bf2v[1], bf2v[2], bf2v[3]};
            dC = __builtin_amdgcn_mfma_f32_16x16x32_bf16(mfrag, uu.v, dC, 0, 0, 0);

            float c20 = fmaxf(dC[0], 0.f), c21 = fmaxf(dC[1], 0.f);
            float c22 = fmaxf(dC[2], 0.f), c23 = fmaxf(dC[3], 0.f);
            float r0 = dF[0] + c20, r1 = dF[1] + c21;
            float r2 = dF[2] + c22, r3 = dF[3] + c23;
            if (!intr) {
                int p = p0 + 16 * (gi0 + it) + lane15;
                if (((p < 1) | (p > LL - 3)) && g >= 2) {
                    r0 = c20; r1 = c21; r2 = c22; r3 = c23;
                }
            }
            o0[16 * it] = r0;
            o1[16 * it] = r1;
            o2[16 * it] = r2;
            o3[16 * it] = r3;

            if (it < 7) {       // slide: chunks 4..7 -> 0..3, read 4 new
                bb[0] = bb[4]; bb[1] = bb[5]; bb[2] = bb[6]; bb[3] = bb[7];
                #pragma unroll
                for (int c = 4; c < 8; ++c)
                    bb[c] = *reinterpret_cast<const bf16x8*>(
                        frow + 16 * 8 * (it + 1) + 32 * c);
            }
        }
    }
}

extern "C" void kernel_launch(void* const* d_in, const int* in_sizes, int n_in,
                              void* d_out, int out_size, void* d_ws, size_t ws_size,
                              hipStream_t stream)
{
    const float* x    = (const float*)d_in[0];
    const float* w00  = (const float*)d_in[1];
    const float* b00  = (const float*)d_in[2];
    const float* w01  = (const float*)d_in[3];
    const float* b01  = (const float*)d_in[4];
    const float* w02  = (const float*)d_in[5];
    const float* b02  = (const float*)d_in[6];
    const float* wc1  = (const float*)d_in[7];
    const float* g1   = (const float*)d_in[8];
    const float* bt1  = (const float*)d_in[9];
    const float* m1   = (const float*)d_in[10];
    const float* v1   = (const float*)d_in[11];
    const float* beta = (const float*)d_in[12];
    const float* wc2  = (const float*)d_in[13];
    const float* g2   = (const float*)d_in[14];
    const float* bt2  = (const float*)d_in[15];
    const float* m2   = (const float*)d_in[16];
    const float* v2   = (const float*)d_in[17];

    char* wsb = (char*)d_ws;
    float* partialp       = (float*)wsb;                       // 2,097,152 B
    unsigned short* Mpp   = (unsigned short*)(wsb + 2097152);  // 262,144 B
    unsigned short* wA0p  = (unsigned short*)(wsb + 2359296);  // 6,144 B
    unsigned short* wA1p  = (unsigned short*)(wsb + 2365440);  // 8,192 B
    unsigned short* wc0Ap = (unsigned short*)(wsb + 2373632);  // 1,024 B
    float* o = (float*)d_out;

    hipLaunchKernelGGL(kernA1, dim3(2048), dim3(256), 0, stream,
        x, wc1, g1, bt1, m1, v1, partialp);
    hipLaunchKernelGGL(kernA2, dim3(256), dim3(256), 0, stream,
        partialp, beta, wc2, g2, bt2, m2, v2, w00, w01, w02,
        wc1, g1, bt1, m1, v1, Mpp, wA0p, wA1p, wc0Ap);
    hipLaunchKernelGGL(kernB, dim3(4096), dim3(256), 0, stream,
        x, b00, b01, b02, g2, bt2, m2, v2,
        wA0p, wA1p, wc0Ap, Mpp, o);
}